// Round 9
// baseline (253.669 us; speedup 1.0000x reference)
//
#include <hip/hip_runtime.h>

#define DIN 128
#define DOUT 64
#define SH 8            // nodes per bucket = 256
#define CAP 8192        // slots per bucket (avg ~4096, +64 sigma headroom)
#define BMAX 512
#define XS_STRIDE (DIN + 4)

typedef unsigned short ushort_t;
typedef float v2f __attribute__((ext_vector_type(2)));

__device__ __forceinline__ ushort_t f2bf(float f) {
    union { float f; unsigned u; } v; v.f = f;
    unsigned r = v.u + 0x7FFF + ((v.u >> 16) & 1);   // round-nearest-even
    return (ushort_t)(r >> 16);
}

// ---------- pass A: bin edges by dst>>SH, packed (ldst<<17)|src ----------
__global__ __launch_bounds__(256) void bin_kernel(const int* __restrict__ src,
                                                  const int* __restrict__ dst,
                                                  int* __restrict__ cursor,
                                                  int* __restrict__ binned, int E, int B) {
    __shared__ int hist_s[BMAX], gbase_s[BMAX], cur_s[BMAX];
    for (int i = threadIdx.x; i < B; i += 256) { hist_s[i] = 0; cur_s[i] = 0; }
    __syncthreads();
    int e0 = blockIdx.x * 4096;
    int e1 = min(e0 + 4096, E);
    for (int e = e0 + threadIdx.x; e < e1; e += 256)
        atomicAdd(&hist_s[dst[e] >> SH], 1);
    __syncthreads();
    for (int b = threadIdx.x; b < B; b += 256) {
        int h = hist_s[b];
        gbase_s[b] = h ? atomicAdd(&cursor[b], h) : 0;
    }
    __syncthreads();
    for (int e = e0 + threadIdx.x; e < e1; e += 256) {
        int d = dst[e], s = src[e];
        int b = d >> SH;
        int off  = atomicAdd(&cur_s[b], 1);
        int slot = gbase_s[b] + off;
        if (slot < (b + 1) * CAP)
            binned[slot] = ((d & ((1 << SH) - 1)) << 17) | s;
    }
}

__global__ void init_cursor_kernel(int* cursor, int B, int* csr_pad) {
    int b = blockIdx.x * 256 + threadIdx.x;
    if (b < B) cursor[b] = b * CAP;
    if (b < 64) csr_pad[b] = 0;
}

// exclusive scan of bucket counts -> bucket_base; row_ptr[N] = total
__global__ __launch_bounds__(BMAX) void bucket_scan_kernel(const int* __restrict__ cursor,
                                                           int* __restrict__ bucket_base,
                                                           int* __restrict__ row_ptr,
                                                           int B, int N) {
    __shared__ int sh[BMAX];
    int t = threadIdx.x;
    int c = 0;
    if (t < B) { c = cursor[t] - t * CAP; if (c > CAP) c = CAP; }
    sh[t] = c;
    __syncthreads();
    for (int off = 1; off < BMAX; off <<= 1) {
        int v = (t >= off) ? sh[t - off] : 0;
        __syncthreads();
        sh[t] += v;
        __syncthreads();
    }
    if (t < B) bucket_base[t] = sh[t] - c;  // exclusive
    if (t == 0) row_ptr[N] = sh[B - 1];     // total (== E)
}

// ---------- pass B: per-bucket CSR build + row_ptr + dinv ----------
__global__ __launch_bounds__(256) void csr_kernel(const int* __restrict__ binned,
                                                  const int* __restrict__ cursor,
                                                  const int* __restrict__ bucket_base,
                                                  int* __restrict__ row_ptr,
                                                  float* __restrict__ dinv,
                                                  int* __restrict__ csr_src, int N) {
    __shared__ int cnt_s[256], off_s[256];
    int b = blockIdx.x;
    int t = threadIdx.x;
    int ecnt = cursor[b] - b * CAP; if (ecnt > CAP) ecnt = CAP;
    int base = bucket_base[b];
    const int* eb = binned + (size_t)b * CAP;
    cnt_s[t] = 0;
    __syncthreads();
    for (int i = t; i < ecnt; i += 256)
        atomicAdd(&cnt_s[eb[i] >> 17], 1);
    __syncthreads();
    int myc = cnt_s[t];
    off_s[t] = myc;
    __syncthreads();
    for (int off = 1; off < 256; off <<= 1) {
        int v = (t >= off) ? off_s[t - off] : 0;
        __syncthreads();
        off_s[t] += v;
        __syncthreads();
    }
    int excl = off_s[t] - myc;
    int node = (b << SH) + t;
    if (node < N) {
        row_ptr[node] = base + excl;
        dinv[node] = rsqrtf((float)myc + 1.0f);  // +1 = self loop
    }
    __syncthreads();
    off_s[t] = base + excl;   // global write cursor for this node
    __syncthreads();
    for (int i = t; i < ecnt; i += 256) {
        int p = eb[i];
        int slot = atomicAdd(&off_s[p >> 17], 1);
        csr_src[slot] = p & 0x1FFFF;
    }
}

// ---------- projection: y0' = dinv * (x @ W^T), stored bf16 ----------
__global__ __launch_bounds__(256) void gemm_kernel(const float* __restrict__ x,
                                                   const float* __restrict__ W,
                                                   const float* __restrict__ dinv,
                                                   ushort_t* __restrict__ yb, int N) {
    __shared__ float Ws[DIN * DOUT];
    __shared__ float xs[64 * XS_STRIDE];
    int tid  = threadIdx.x;
    int row0 = blockIdx.x * 64;

    for (int j = tid; j < DIN * DOUT; j += 256)
        Ws[j] = W[(j & 63) * DIN + (j >> 6)];

    for (int j = tid; j < 64 * DIN / 4; j += 256) {
        int r  = j >> 5;
        int c4 = (j & 31) * 4;
        int grow = row0 + r;
        float4 v = {0.f, 0.f, 0.f, 0.f};
        if (grow < N) v = *(const float4*)&x[(size_t)grow * DIN + c4];
        *(float4*)&xs[r * XS_STRIDE + c4] = v;
    }
    __syncthreads();

    int g    = tid & 15;
    int rgl  = (tid >> 4) & 3;
    int wave = tid >> 6;
    int rloc = wave * 16 + rgl * 4;

    float4 acc[4] = {};
    for (int kk = 0; kk < DIN; kk += 4) {
        float4 wv0 = *(const float4*)&Ws[(kk + 0) * DOUT + g * 4];
        float4 wv1 = *(const float4*)&Ws[(kk + 1) * DOUT + g * 4];
        float4 wv2 = *(const float4*)&Ws[(kk + 2) * DOUT + g * 4];
        float4 wv3 = *(const float4*)&Ws[(kk + 3) * DOUT + g * 4];
        #pragma unroll
        for (int r = 0; r < 4; ++r) {
            float4 xv = *(const float4*)&xs[(rloc + r) * XS_STRIDE + kk];
            acc[r].x += xv.x * wv0.x + xv.y * wv1.x + xv.z * wv2.x + xv.w * wv3.x;
            acc[r].y += xv.x * wv0.y + xv.y * wv1.y + xv.z * wv2.y + xv.w * wv3.y;
            acc[r].z += xv.x * wv0.z + xv.y * wv1.z + xv.z * wv2.z + xv.w * wv3.z;
            acc[r].w += xv.x * wv0.w + xv.y * wv1.w + xv.z * wv2.w + xv.w * wv3.w;
        }
    }
    #pragma unroll
    for (int r = 0; r < 4; ++r) {
        int grow = row0 + rloc + r;
        if (grow < N) {
            float dv = dinv[grow];
            ushort4 o;
            o.x = f2bf(acc[r].x * dv); o.y = f2bf(acc[r].y * dv);
            o.z = f2bf(acc[r].z * dv); o.w = f2bf(acc[r].w * dv);
            *(ushort4*)&yb[(size_t)grow * DOUT + g * 4] = o;
        }
    }
}

// unpack 4 dwords (8 bf16) and add into v2f acc pairs (coax v_pk_add_f32)
__device__ __forceinline__ void add_unpack2(v2f* acc, uint4 v) {
    unsigned u[4] = {v.x, v.y, v.z, v.w};
    #pragma unroll
    for (int d = 0; d < 4; ++d) {
        union { unsigned u; float f; } lo, hi;
        lo.u = u[d] << 16;
        hi.u = u[d] & 0xFFFF0000u;
        v2f p; p.x = lo.f; p.y = hi.f;
        acc[d] += p;
    }
}

// ---------- wide pull-gather: wave = 8 slots x 8 feature-blocks ----------
// One dwordx4 fetches 8 different src rows. csr_src loaded once per 64 edges
// (coalesced), broadcast per-batch via ds_bpermute. 32-bit saddr addressing.
template <int FINAL>
__global__ __launch_bounds__(256) void gather_kernel(const int* __restrict__ row_ptr,
                                                     const int* __restrict__ csr_src,
                                                     const float* __restrict__ dinv,
                                                     const ushort_t* __restrict__ yin,
                                                     const float* __restrict__ bias,
                                                     ushort_t* __restrict__ yout,
                                                     float* __restrict__ out,
                                                     float* __restrict__ emb, int N) {
    int row = blockIdx.x * 4 + (threadIdx.x >> 6);
    if (row >= N) return;
    int lane = threadIdx.x & 63;
    int fb   = lane & 7;    // feature block: features [fb*8, fb*8+8)
    int slot = lane >> 3;   // edge slot within a batch of 8
    int start = __builtin_amdgcn_readfirstlane(row_ptr[row]);
    int end   = __builtin_amdgcn_readfirstlane(row_ptr[row + 1]);

    const char* ybase = (const char*)yin;
    unsigned fb16 = (unsigned)fb * 16;

    v2f acc2[4] = {};

    // self loop: all lanes load row's fb-block, slot 0 accumulates
    {
        uint4 sv = *(const uint4*)(ybase + (((unsigned)row << 7) + fb16));
        if (slot == 0) add_unpack2(acc2, sv);
    }

    int g0 = start;
    // full 64-edge groups: no masking, unrolled 8 -> 8 independent load chains
    for (; g0 + 64 <= end; g0 += 64) {
        int sidx = csr_src[g0 + lane];           // 1 coalesced load / 64 edges
        #pragma unroll
        for (int bb = 0; bb < 8; ++bb) {
            int s = __shfl(sidx, bb * 8 + slot, 64);   // ds_bpermute
            uint4 v = *(const uint4*)(ybase + (((unsigned)s << 7) + fb16));
            add_unpack2(acc2, v);
        }
    }
    // tail group (masked)
    if (g0 < end) {
        int nb = end - g0;
        int li = g0 + (lane < nb ? lane : nb - 1);
        int sidx = csr_src[li];
        int nbatch = (nb + 7) >> 3;
        for (int bb = 0; bb < nbatch; ++bb) {
            int s = __shfl(sidx, bb * 8 + slot, 64);
            uint4 v = *(const uint4*)(ybase + (((unsigned)s << 7) + fb16));
            if (bb * 8 + slot < nb) add_unpack2(acc2, v);
        }
    }

    float acc[8] = {acc2[0].x, acc2[0].y, acc2[1].x, acc2[1].y,
                    acc2[2].x, acc2[2].y, acc2[3].x, acc2[3].y};

    // sum the 8 slots: xor over slot bits
    #pragma unroll
    for (int m = 8; m <= 32; m <<= 1) {
        #pragma unroll
        for (int i = 0; i < 8; ++i) acc[i] += __shfl_xor(acc[i], m, 64);
    }

    float dv = dinv[row];
    if (!FINAL) {
        if (slot == 0) {
            float s2 = dv * dv;
            union { ushort_t us[8]; uint4 u; } o;
            #pragma unroll
            for (int i = 0; i < 8; ++i) o.us[i] = f2bf(acc[i] * s2);
            *(uint4*)(yout + (size_t)row * DOUT + fb * 8) = o.u;
        }
    } else {
        const float4* bp = (const float4*)(bias + fb * 8);
        float4 b0 = bp[0], b1 = bp[1];
        float e[8];
        e[0] = dv * acc[0] + b0.x; e[1] = dv * acc[1] + b0.y;
        e[2] = dv * acc[2] + b0.z; e[3] = dv * acc[3] + b0.w;
        e[4] = dv * acc[4] + b1.x; e[5] = dv * acc[5] + b1.y;
        e[6] = dv * acc[6] + b1.z; e[7] = dv * acc[7] + b1.w;
        float m = e[0];
        #pragma unroll
        for (int i = 1; i < 8; ++i) m = fmaxf(m, e[i]);
        #pragma unroll
        for (int o2 = 1; o2 <= 4; o2 <<= 1) m = fmaxf(m, __shfl_xor(m, o2, 64));
        float ss = 0.f;
        #pragma unroll
        for (int i = 0; i < 8; ++i) ss += expf(e[i] - m);
        #pragma unroll
        for (int o2 = 1; o2 <= 4; o2 <<= 1) ss += __shfl_xor(ss, o2, 64);
        float lg = m + logf(ss);
        if (slot == 0) {
            float4* ep = (float4*)(emb + (size_t)row * DOUT + fb * 8);
            ep[0] = make_float4(e[0], e[1], e[2], e[3]);
            ep[1] = make_float4(e[4], e[5], e[6], e[7]);
            float4* op = (float4*)(out + (size_t)row * DOUT + fb * 8);
            op[0] = make_float4(e[0] - lg, e[1] - lg, e[2] - lg, e[3] - lg);
            op[1] = make_float4(e[4] - lg, e[5] - lg, e[6] - lg, e[7] - lg);
        }
    }
}

extern "C" void kernel_launch(void* const* d_in, const int* in_sizes, int n_in,
                              void* d_out, int out_size, void* d_ws, size_t ws_size,
                              hipStream_t stream) {
    const float* x    = (const float*)d_in[0];
    const int*   edge = (const int*)d_in[1];
    const float* W    = (const float*)d_in[2];
    const float* b    = (const float*)d_in[3];

    const int N = in_sizes[0] / DIN;   // 100000
    const int E = in_sizes[1] / 2;     // 1600000
    const int* src = edge;
    const int* dst = edge + E;

    float* out_ptr = (float*)d_out;                // [N,64] log_softmax
    float* emb_ptr = out_ptr + (size_t)N * DOUT;   // [N,64] emb

    const int B = (N + (1 << SH) - 1) >> SH;       // 391 buckets

    // workspace (~33 MB):
    //   cursor[512] | bucket_base[512] | row_ptr[N+1] | dinv[N] | csr_src[E+64] |
    //   arena: binned[B*CAP] ints (CSR build) aliased with y0b,y1b bf16 (gathers)
    int*     cursor      = (int*)d_ws;
    int*     bucket_base = cursor + BMAX;
    int*     row_ptr     = bucket_base + BMAX;
    float*   dinv        = (float*)(row_ptr + N + 1);
    int*     csr_src     = (int*)(dinv + N);
    int*     arena       = csr_src + E + 64;        // +64: clamped tail-group loads
    int*     binned      = arena;
    ushort_t* y0b        = (ushort_t*)arena;        // aliases binned (dead after csr_kernel)
    ushort_t* y1b        = y0b + (size_t)N * DOUT;

    // 1. CSR by dst + dinv
    init_cursor_kernel<<<(B + 255) / 256, 256, 0, stream>>>(cursor, B, csr_src + E);
    bin_kernel<<<(E + 4095) / 4096, 256, 0, stream>>>(src, dst, cursor, binned, E, B);
    bucket_scan_kernel<<<1, BMAX, 0, stream>>>(cursor, bucket_base, row_ptr, B, N);
    csr_kernel<<<B, 256, 0, stream>>>(binned, cursor, bucket_base, row_ptr, dinv, csr_src, N);

    // 2. project + pre-scale: y0' = dinv * (x @ W^T)   (bf16)
    gemm_kernel<<<(N + 63) / 64, 256, 0, stream>>>(x, W, dinv, y0b, N);

    // 3. hop 1: y1' = dinv^2 * (y0'[row] + sum y0'[src])
    gather_kernel<0><<<(N + 3) / 4, 256, 0, stream>>>(row_ptr, csr_src, dinv, y0b, b,
                                                      y1b, nullptr, nullptr, N);

    // 4. hop 2 + bias + log_softmax, fused
    gather_kernel<1><<<(N + 3) / 4, 256, 0, stream>>>(row_ptr, csr_src, dinv, y1b, b,
                                                      nullptr, out_ptr, emb_ptr, N);
}

// Round 10
// 224.406 us; speedup vs baseline: 1.1304x; 1.1304x over previous
//
#include <hip/hip_runtime.h>

#define DIN 128
#define DOUT 64
#define SH 8            // nodes per bucket = 256
#define CAP 8192        // slots per bucket (avg ~4096, +64 sigma headroom)
#define BMAX 512
#define XS_STRIDE (DIN + 4)

typedef unsigned short ushort_t;
typedef float v2f __attribute__((ext_vector_type(2)));

__device__ __forceinline__ ushort_t f2bf(float f) {
    union { float f; unsigned u; } v; v.f = f;
    unsigned r = v.u + 0x7FFF + ((v.u >> 16) & 1);   // round-nearest-even
    return (ushort_t)(r >> 16);
}

// ---------- pass A: bin edges by dst>>SH, packed (ldst<<17)|src ----------
__global__ __launch_bounds__(256) void bin_kernel(const int* __restrict__ src,
                                                  const int* __restrict__ dst,
                                                  int* __restrict__ cursor,
                                                  int* __restrict__ binned, int E, int B) {
    __shared__ int hist_s[BMAX], gbase_s[BMAX], cur_s[BMAX];
    for (int i = threadIdx.x; i < B; i += 256) { hist_s[i] = 0; cur_s[i] = 0; }
    __syncthreads();
    int e0 = blockIdx.x * 4096;
    int e1 = min(e0 + 4096, E);
    for (int e = e0 + threadIdx.x; e < e1; e += 256)
        atomicAdd(&hist_s[dst[e] >> SH], 1);
    __syncthreads();
    for (int b = threadIdx.x; b < B; b += 256) {
        int h = hist_s[b];
        gbase_s[b] = h ? atomicAdd(&cursor[b], h) : 0;
    }
    __syncthreads();
    for (int e = e0 + threadIdx.x; e < e1; e += 256) {
        int d = dst[e], s = src[e];
        int b = d >> SH;
        int off  = atomicAdd(&cur_s[b], 1);
        int slot = gbase_s[b] + off;
        if (slot < (b + 1) * CAP)
            binned[slot] = ((d & ((1 << SH) - 1)) << 17) | s;
    }
}

// init ALL BMAX cursors (csr_kernel's inline scan reads all 512)
__global__ void init_cursor_kernel(int* cursor, int* csr_pad) {
    int b = blockIdx.x * 256 + threadIdx.x;
    if (b < BMAX) cursor[b] = b * CAP;
    if (b < 64) csr_pad[b] = 0;
}

// ---------- pass B: per-bucket CSR build + inline bucket scan + row_ptr + dinv ----------
__global__ __launch_bounds__(256) void csr_kernel(const int* __restrict__ binned,
                                                  const int* __restrict__ cursor,
                                                  int* __restrict__ row_ptr,
                                                  float* __restrict__ dinv,
                                                  int* __restrict__ csr_src, int N) {
    __shared__ int cnt_s[256], off_s[256], bsc[BMAX];
    int b = blockIdx.x;
    int t = threadIdx.x;

    // inline exclusive scan over all bucket counts (each block redundantly, LDS)
    int c0 = cursor[t] - t * CAP;                 if (c0 > CAP) c0 = CAP;
    int c1 = cursor[t + 256] - (t + 256) * CAP;   if (c1 > CAP) c1 = CAP;
    bsc[t] = c0; bsc[t + 256] = c1;
    __syncthreads();
    for (int off = 1; off < BMAX; off <<= 1) {
        int v0 = (t >= off) ? bsc[t - off] : 0;
        int v1 = (t + 256 >= off) ? bsc[t + 256 - off] : 0;
        __syncthreads();
        bsc[t] += v0; bsc[t + 256] += v1;
        __syncthreads();
    }
    int cb = cursor[b] - b * CAP; if (cb > CAP) cb = CAP;   // this bucket's count
    int base = bsc[b] - cb;                                  // exclusive prefix
    int ecnt = cb;
    const int* eb = binned + (size_t)b * CAP;

    cnt_s[t] = 0;
    __syncthreads();
    for (int i = t; i < ecnt; i += 256)
        atomicAdd(&cnt_s[eb[i] >> 17], 1);
    __syncthreads();
    int myc = cnt_s[t];
    off_s[t] = myc;
    __syncthreads();
    for (int off = 1; off < 256; off <<= 1) {
        int v = (t >= off) ? off_s[t - off] : 0;
        __syncthreads();
        off_s[t] += v;
        __syncthreads();
    }
    int excl = off_s[t] - myc;
    int node = (b << SH) + t;
    if (node < N) {
        row_ptr[node] = base + excl;
        dinv[node] = rsqrtf((float)myc + 1.0f);  // +1 = self loop
        if (node == N - 1) row_ptr[N] = base + excl + myc;   // sentinel == E
    }
    __syncthreads();
    off_s[t] = base + excl;   // global write cursor for this node
    __syncthreads();
    for (int i = t; i < ecnt; i += 256) {
        int p = eb[i];
        int slot = atomicAdd(&off_s[p >> 17], 1);
        csr_src[slot] = p & 0x1FFFF;
    }
}

// ---------- projection: y0' = dinv * (x @ W^T), stored bf16 ----------
__global__ __launch_bounds__(256) void gemm_kernel(const float* __restrict__ x,
                                                   const float* __restrict__ W,
                                                   const float* __restrict__ dinv,
                                                   ushort_t* __restrict__ yb, int N) {
    __shared__ float Ws[DIN * DOUT];
    __shared__ float xs[64 * XS_STRIDE];
    int tid  = threadIdx.x;
    int row0 = blockIdx.x * 64;

    for (int j = tid; j < DIN * DOUT; j += 256)
        Ws[j] = W[(j & 63) * DIN + (j >> 6)];

    for (int j = tid; j < 64 * DIN / 4; j += 256) {
        int r  = j >> 5;
        int c4 = (j & 31) * 4;
        int grow = row0 + r;
        float4 v = {0.f, 0.f, 0.f, 0.f};
        if (grow < N) v = *(const float4*)&x[(size_t)grow * DIN + c4];
        *(float4*)&xs[r * XS_STRIDE + c4] = v;
    }
    __syncthreads();

    int g    = tid & 15;
    int rgl  = (tid >> 4) & 3;
    int wave = tid >> 6;
    int rloc = wave * 16 + rgl * 4;

    float4 acc[4] = {};
    for (int kk = 0; kk < DIN; kk += 4) {
        float4 wv0 = *(const float4*)&Ws[(kk + 0) * DOUT + g * 4];
        float4 wv1 = *(const float4*)&Ws[(kk + 1) * DOUT + g * 4];
        float4 wv2 = *(const float4*)&Ws[(kk + 2) * DOUT + g * 4];
        float4 wv3 = *(const float4*)&Ws[(kk + 3) * DOUT + g * 4];
        #pragma unroll
        for (int r = 0; r < 4; ++r) {
            float4 xv = *(const float4*)&xs[(rloc + r) * XS_STRIDE + kk];
            acc[r].x += xv.x * wv0.x + xv.y * wv1.x + xv.z * wv2.x + xv.w * wv3.x;
            acc[r].y += xv.x * wv0.y + xv.y * wv1.y + xv.z * wv2.y + xv.w * wv3.y;
            acc[r].z += xv.x * wv0.z + xv.y * wv1.z + xv.z * wv2.z + xv.w * wv3.z;
            acc[r].w += xv.x * wv0.w + xv.y * wv1.w + xv.z * wv2.w + xv.w * wv3.w;
        }
    }
    #pragma unroll
    for (int r = 0; r < 4; ++r) {
        int grow = row0 + rloc + r;
        if (grow < N) {
            float dv = dinv[grow];
            ushort4 o;
            o.x = f2bf(acc[r].x * dv); o.y = f2bf(acc[r].y * dv);
            o.z = f2bf(acc[r].z * dv); o.w = f2bf(acc[r].w * dv);
            *(ushort4*)&yb[(size_t)grow * DOUT + g * 4] = o;
        }
    }
}

// unpack 4 dwords (8 bf16) and add into v2f acc pairs (v_pk_add_f32)
__device__ __forceinline__ void add_unpack2(v2f* acc, uint4 v) {
    unsigned u[4] = {v.x, v.y, v.z, v.w};
    #pragma unroll
    for (int d = 0; d < 4; ++d) {
        union { unsigned u; float f; } lo, hi;
        lo.u = u[d] << 16;
        hi.u = u[d] & 0xFFFF0000u;
        v2f p; p.x = lo.f; p.y = hi.f;
        acc[d] += p;
    }
}

// ---------- wide pull-gather (round-8 structure): wave = 8 slots x 8 fb ----------
// One dwordx4 fetches 8 different src rows. Full batches unmasked; one masked tail.
template <int FINAL>
__global__ __launch_bounds__(256) void gather_kernel(const int* __restrict__ row_ptr,
                                                     const int* __restrict__ csr_src,
                                                     const float* __restrict__ dinv,
                                                     const ushort_t* __restrict__ yin,
                                                     const float* __restrict__ bias,
                                                     ushort_t* __restrict__ yout,
                                                     float* __restrict__ out,
                                                     float* __restrict__ emb, int N) {
    int row = blockIdx.x * 4 + (threadIdx.x >> 6);
    if (row >= N) return;
    int lane = threadIdx.x & 63;
    int fb   = lane & 7;    // feature block: features [fb*8, fb*8+8)
    int slot = lane >> 3;   // edge slot within a batch of 8
    int start = __builtin_amdgcn_readfirstlane(row_ptr[row]);
    int end   = __builtin_amdgcn_readfirstlane(row_ptr[row + 1]);

    const char* ybase = (const char*)yin;
    unsigned fb16 = (unsigned)fb * 16u;

    v2f acc2[4] = {};

    // self loop: all lanes load row's fb-block, slot 0 accumulates
    {
        uint4 sv = *(const uint4*)(ybase + (((unsigned)row << 7) + fb16));
        if (slot == 0) add_unpack2(acc2, sv);
    }

    int b = start;
    int nfull = (end - start) >> 3;
    for (int i = 0; i < nfull; ++i, b += 8) {        // unmasked full batches
        int s = csr_src[b + slot];                   // 32B span per batch
        uint4 v = *(const uint4*)(ybase + (((unsigned)s << 7) + fb16));
        add_unpack2(acc2, v);
    }
    int rem = end - b;
    if (rem > 0) {                                   // one masked tail batch
        int ei = b + slot;
        int eidx = (ei < end) ? ei : end - 1;        // clamp: dup line, no new miss
        int s = csr_src[eidx];
        uint4 v = *(const uint4*)(ybase + (((unsigned)s << 7) + fb16));
        if (slot < rem) add_unpack2(acc2, v);
    }

    float acc[8] = {acc2[0].x, acc2[0].y, acc2[1].x, acc2[1].y,
                    acc2[2].x, acc2[2].y, acc2[3].x, acc2[3].y};

    // sum the 8 slots: xor over slot bits
    #pragma unroll
    for (int m = 8; m <= 32; m <<= 1) {
        #pragma unroll
        for (int i = 0; i < 8; ++i) acc[i] += __shfl_xor(acc[i], m, 64);
    }

    float dv = dinv[row];
    if (!FINAL) {
        if (slot == 0) {
            float s2 = dv * dv;
            union { ushort_t us[8]; uint4 u; } o;
            #pragma unroll
            for (int i = 0; i < 8; ++i) o.us[i] = f2bf(acc[i] * s2);
            *(uint4*)(yout + (size_t)row * DOUT + fb * 8) = o.u;
        }
    } else {
        const float4* bp = (const float4*)(bias + fb * 8);
        float4 b0 = bp[0], b1 = bp[1];
        float e[8];
        e[0] = dv * acc[0] + b0.x; e[1] = dv * acc[1] + b0.y;
        e[2] = dv * acc[2] + b0.z; e[3] = dv * acc[3] + b0.w;
        e[4] = dv * acc[4] + b1.x; e[5] = dv * acc[5] + b1.y;
        e[6] = dv * acc[6] + b1.z; e[7] = dv * acc[7] + b1.w;
        float m = e[0];
        #pragma unroll
        for (int i = 1; i < 8; ++i) m = fmaxf(m, e[i]);
        #pragma unroll
        for (int o2 = 1; o2 <= 4; o2 <<= 1) m = fmaxf(m, __shfl_xor(m, o2, 64));
        float ss = 0.f;
        #pragma unroll
        for (int i = 0; i < 8; ++i) ss += expf(e[i] - m);
        #pragma unroll
        for (int o2 = 1; o2 <= 4; o2 <<= 1) ss += __shfl_xor(ss, o2, 64);
        float lg = m + logf(ss);
        if (slot == 0) {
            float4* ep = (float4*)(emb + (size_t)row * DOUT + fb * 8);
            ep[0] = make_float4(e[0], e[1], e[2], e[3]);
            ep[1] = make_float4(e[4], e[5], e[6], e[7]);
            float4* op = (float4*)(out + (size_t)row * DOUT + fb * 8);
            op[0] = make_float4(e[0] - lg, e[1] - lg, e[2] - lg, e[3] - lg);
            op[1] = make_float4(e[4] - lg, e[5] - lg, e[6] - lg, e[7] - lg);
        }
    }
}

extern "C" void kernel_launch(void* const* d_in, const int* in_sizes, int n_in,
                              void* d_out, int out_size, void* d_ws, size_t ws_size,
                              hipStream_t stream) {
    const float* x    = (const float*)d_in[0];
    const int*   edge = (const int*)d_in[1];
    const float* W    = (const float*)d_in[2];
    const float* b    = (const float*)d_in[3];

    const int N = in_sizes[0] / DIN;   // 100000
    const int E = in_sizes[1] / 2;     // 1600000
    const int* src = edge;
    const int* dst = edge + E;

    float* out_ptr = (float*)d_out;                // [N,64] log_softmax
    float* emb_ptr = out_ptr + (size_t)N * DOUT;   // [N,64] emb

    const int B = (N + (1 << SH) - 1) >> SH;       // 391 buckets

    // workspace (~33 MB):
    //   cursor[512] | row_ptr[N+1] | dinv[N] | csr_src[E+64] |
    //   arena: binned[B*CAP] ints (CSR build) aliased with y0b,y1b bf16 (gathers)
    int*     cursor      = (int*)d_ws;
    int*     row_ptr     = cursor + BMAX;
    float*   dinv        = (float*)(row_ptr + N + 1);
    int*     csr_src     = (int*)(dinv + N);
    int*     arena       = csr_src + E + 64;        // +64: clamped tail-group loads
    int*     binned      = arena;
    ushort_t* y0b        = (ushort_t*)arena;        // aliases binned (dead after csr_kernel)
    ushort_t* y1b        = y0b + (size_t)N * DOUT;

    // 1. CSR by dst + dinv (scan inlined in csr_kernel)
    init_cursor_kernel<<<2, 256, 0, stream>>>(cursor, csr_src + E);
    bin_kernel<<<(E + 4095) / 4096, 256, 0, stream>>>(src, dst, cursor, binned, E, B);
    csr_kernel<<<B, 256, 0, stream>>>(binned, cursor, row_ptr, dinv, csr_src, N);

    // 2. project + pre-scale: y0' = dinv * (x @ W^T)   (bf16)
    gemm_kernel<<<(N + 63) / 64, 256, 0, stream>>>(x, W, dinv, y0b, N);

    // 3. hop 1: y1' = dinv^2 * (y0'[row] + sum y0'[src])
    gather_kernel<0><<<(N + 3) / 4, 256, 0, stream>>>(row_ptr, csr_src, dinv, y0b, b,
                                                      y1b, nullptr, nullptr, N);

    // 4. hop 2 + bias + log_softmax, fused
    gather_kernel<1><<<(N + 3) / 4, 256, 0, stream>>>(row_ptr, csr_src, dinv, y1b, b,
                                                      nullptr, out_ptr, emb_ptr, N);
}

// Round 11
// 203.441 us; speedup vs baseline: 1.2469x; 1.1031x over previous
//
#include <hip/hip_runtime.h>

#define DIN 128
#define DOUT 64
#define SH 8            // nodes per bucket = 256
#define CAP 8192        // slots per bucket (avg ~4096, +64 sigma headroom)
#define BMAX 512
#define XS_STRIDE (DIN + 4)
#define XROWS 32        // x tile rows (LDS 49.6KB total -> 3 blocks/CU)

typedef unsigned short ushort_t;
typedef float v2f __attribute__((ext_vector_type(2)));

__device__ __forceinline__ ushort_t f2bf(float f) {
    union { float f; unsigned u; } v; v.f = f;
    unsigned r = v.u + 0x7FFF + ((v.u >> 16) & 1);   // round-nearest-even
    return (ushort_t)(r >> 16);
}

// ---------- pass A: bin edges by dst>>SH, packed (ldst<<17)|src ----------
__global__ __launch_bounds__(256) void bin_kernel(const int* __restrict__ src,
                                                  const int* __restrict__ dst,
                                                  int* __restrict__ cursor,
                                                  int* __restrict__ binned, int E, int B) {
    __shared__ int hist_s[BMAX], gbase_s[BMAX], cur_s[BMAX];
    for (int i = threadIdx.x; i < B; i += 256) { hist_s[i] = 0; cur_s[i] = 0; }
    __syncthreads();
    int e0 = blockIdx.x * 4096;
    int e1 = min(e0 + 4096, E);
    for (int e = e0 + threadIdx.x; e < e1; e += 256)
        atomicAdd(&hist_s[dst[e] >> SH], 1);
    __syncthreads();
    for (int b = threadIdx.x; b < B; b += 256) {
        int h = hist_s[b];
        gbase_s[b] = h ? atomicAdd(&cursor[b], h) : 0;
    }
    __syncthreads();
    for (int e = e0 + threadIdx.x; e < e1; e += 256) {
        int d = dst[e], s = src[e];
        int b = d >> SH;
        int off  = atomicAdd(&cur_s[b], 1);
        int slot = gbase_s[b] + off;
        if (slot < (b + 1) * CAP)
            binned[slot] = ((d & ((1 << SH) - 1)) << 17) | s;
    }
}

// init ALL BMAX cursors + zero csr pad + transpose W -> WT [128][64]
__global__ void init_cursor_kernel(int* cursor, int* csr_pad,
                                   const float* __restrict__ W, float* __restrict__ WT) {
    int b = blockIdx.x * 256 + threadIdx.x;
    if (b < BMAX) cursor[b] = b * CAP;
    if (b < 64) csr_pad[b] = 0;
    // 8192 elems over 2048 threads: 4 each. j = k*64+o ; WT[j] = W[o*128+k]
    for (int j = b; j < DIN * DOUT; j += 2048)
        WT[j] = W[(j & 63) * DIN + (j >> 6)];
}

// ---------- pass B: per-bucket CSR build + inline bucket scan + row_ptr + dinv ----------
__global__ __launch_bounds__(256) void csr_kernel(const int* __restrict__ binned,
                                                  const int* __restrict__ cursor,
                                                  int* __restrict__ row_ptr,
                                                  float* __restrict__ dinv,
                                                  int* __restrict__ csr_src, int N) {
    __shared__ int cnt_s[256], off_s[256], bsc[BMAX];
    int b = blockIdx.x;
    int t = threadIdx.x;

    // inline exclusive scan over all bucket counts (each block redundantly, LDS)
    int c0 = cursor[t] - t * CAP;                 if (c0 > CAP) c0 = CAP;
    int c1 = cursor[t + 256] - (t + 256) * CAP;   if (c1 > CAP) c1 = CAP;
    bsc[t] = c0; bsc[t + 256] = c1;
    __syncthreads();
    for (int off = 1; off < BMAX; off <<= 1) {
        int v0 = (t >= off) ? bsc[t - off] : 0;
        int v1 = (t + 256 >= off) ? bsc[t + 256 - off] : 0;
        __syncthreads();
        bsc[t] += v0; bsc[t + 256] += v1;
        __syncthreads();
    }
    int cb = cursor[b] - b * CAP; if (cb > CAP) cb = CAP;   // this bucket's count
    int base = bsc[b] - cb;                                  // exclusive prefix
    int ecnt = cb;
    const int* eb = binned + (size_t)b * CAP;

    cnt_s[t] = 0;
    __syncthreads();
    for (int i = t; i < ecnt; i += 256)
        atomicAdd(&cnt_s[eb[i] >> 17], 1);
    __syncthreads();
    int myc = cnt_s[t];
    off_s[t] = myc;
    __syncthreads();
    for (int off = 1; off < 256; off <<= 1) {
        int v = (t >= off) ? off_s[t - off] : 0;
        __syncthreads();
        off_s[t] += v;
        __syncthreads();
    }
    int excl = off_s[t] - myc;
    int node = (b << SH) + t;
    if (node < N) {
        row_ptr[node] = base + excl;
        dinv[node] = rsqrtf((float)myc + 1.0f);  // +1 = self loop
        if (node == N - 1) row_ptr[N] = base + excl + myc;   // sentinel == E
    }
    __syncthreads();
    off_s[t] = base + excl;   // global write cursor for this node
    __syncthreads();
    for (int i = t; i < ecnt; i += 256) {
        int p = eb[i];
        int slot = atomicAdd(&off_s[p >> 17], 1);
        csr_src[slot] = p & 0x1FFFF;
    }
}

// ---------- projection: y0' = dinv * (x @ W^T), stored bf16 ----------
// 32-row tile, WT pre-transposed: LDS 49.6KB -> 3 blocks/CU.
// thread = 2 rows x 4 cols: g = tid&15 (cols g*4..), rg = tid>>4 (rows rg*2, rg*2+1)
__global__ __launch_bounds__(256) void gemm_kernel(const float* __restrict__ x,
                                                   const float* __restrict__ WT,
                                                   const float* __restrict__ dinv,
                                                   ushort_t* __restrict__ yb, int N) {
    __shared__ float Ws[DIN * DOUT];              // 32 KB, [k][o] (already transposed)
    __shared__ float xs[XROWS * XS_STRIDE];       // 16.9 KB
    int tid  = threadIdx.x;
    int row0 = blockIdx.x * XROWS;

    // stage WT: fully linear float4 both sides
    {
        const float4* s4 = (const float4*)WT;
        float4* d4 = (float4*)Ws;
        for (int j = tid; j < DIN * DOUT / 4; j += 256) d4[j] = s4[j];
    }
    // stage x tile: coalesced float4
    for (int j = tid; j < XROWS * DIN / 4; j += 256) {
        int r  = j >> 5;
        int c4 = (j & 31) * 4;
        int grow = row0 + r;
        float4 v = {0.f, 0.f, 0.f, 0.f};
        if (grow < N) v = *(const float4*)&x[(size_t)grow * DIN + c4];
        *(float4*)&xs[r * XS_STRIDE + c4] = v;
    }
    __syncthreads();

    int g  = tid & 15;
    int rg = tid >> 4;
    int r0 = rg * 2;

    float4 acc0 = {}, acc1 = {};
    for (int kk = 0; kk < DIN; kk += 4) {
        float4 wv0 = *(const float4*)&Ws[(kk + 0) * DOUT + g * 4];
        float4 wv1 = *(const float4*)&Ws[(kk + 1) * DOUT + g * 4];
        float4 wv2 = *(const float4*)&Ws[(kk + 2) * DOUT + g * 4];
        float4 wv3 = *(const float4*)&Ws[(kk + 3) * DOUT + g * 4];
        float4 xv0 = *(const float4*)&xs[(r0 + 0) * XS_STRIDE + kk];
        float4 xv1 = *(const float4*)&xs[(r0 + 1) * XS_STRIDE + kk];
        acc0.x += xv0.x * wv0.x + xv0.y * wv1.x + xv0.z * wv2.x + xv0.w * wv3.x;
        acc0.y += xv0.x * wv0.y + xv0.y * wv1.y + xv0.z * wv2.y + xv0.w * wv3.y;
        acc0.z += xv0.x * wv0.z + xv0.y * wv1.z + xv0.z * wv2.z + xv0.w * wv3.z;
        acc0.w += xv0.x * wv0.w + xv0.y * wv1.w + xv0.z * wv2.w + xv0.w * wv3.w;
        acc1.x += xv1.x * wv0.x + xv1.y * wv1.x + xv1.z * wv2.x + xv1.w * wv3.x;
        acc1.y += xv1.x * wv0.y + xv1.y * wv1.y + xv1.z * wv2.y + xv1.w * wv3.y;
        acc1.z += xv1.x * wv0.z + xv1.y * wv1.z + xv1.z * wv2.z + xv1.w * wv3.z;
        acc1.w += xv1.x * wv0.w + xv1.y * wv1.w + xv1.z * wv2.w + xv1.w * wv3.w;
    }
    #pragma unroll
    for (int r = 0; r < 2; ++r) {
        int grow = row0 + r0 + r;
        if (grow < N) {
            float dv = dinv[grow];
            float4 a = r ? acc1 : acc0;
            ushort4 o;
            o.x = f2bf(a.x * dv); o.y = f2bf(a.y * dv);
            o.z = f2bf(a.z * dv); o.w = f2bf(a.w * dv);
            *(ushort4*)&yb[(size_t)grow * DOUT + g * 4] = o;
        }
    }
}

// unpack 4 dwords (8 bf16) and add into v2f acc pairs (v_pk_add_f32)
__device__ __forceinline__ void add_unpack2(v2f* acc, uint4 v) {
    unsigned u[4] = {v.x, v.y, v.z, v.w};
    #pragma unroll
    for (int d = 0; d < 4; ++d) {
        union { unsigned u; float f; } lo, hi;
        lo.u = u[d] << 16;
        hi.u = u[d] & 0xFFFF0000u;
        v2f p; p.x = lo.f; p.y = hi.f;
        acc[d] += p;
    }
}

// ---------- wide pull-gather: wave = 8 slots x 8 fb ----------
template <int FINAL>
__global__ __launch_bounds__(256) void gather_kernel(const int* __restrict__ row_ptr,
                                                     const int* __restrict__ csr_src,
                                                     const float* __restrict__ dinv,
                                                     const ushort_t* __restrict__ yin,
                                                     const float* __restrict__ bias,
                                                     ushort_t* __restrict__ yout,
                                                     float* __restrict__ out,
                                                     float* __restrict__ emb, int N) {
    int row = blockIdx.x * 4 + (threadIdx.x >> 6);
    if (row >= N) return;
    int lane = threadIdx.x & 63;
    int fb   = lane & 7;    // feature block: features [fb*8, fb*8+8)
    int slot = lane >> 3;   // edge slot within a batch of 8
    int start = __builtin_amdgcn_readfirstlane(row_ptr[row]);
    int end   = __builtin_amdgcn_readfirstlane(row_ptr[row + 1]);

    const char* ybase = (const char*)yin;
    unsigned fb16 = (unsigned)fb * 16u;

    v2f acc2[4] = {};

    // self loop: all lanes load row's fb-block, slot 0 accumulates
    {
        uint4 sv = *(const uint4*)(ybase + (((unsigned)row << 7) + fb16));
        if (slot == 0) add_unpack2(acc2, sv);
    }

    int b = start;
    int nfull = (end - start) >> 3;
    for (int i = 0; i < nfull; ++i, b += 8) {        // unmasked full batches
        int s = csr_src[b + slot];                   // 32B span per batch
        uint4 v = *(const uint4*)(ybase + (((unsigned)s << 7) + fb16));
        add_unpack2(acc2, v);
    }
    int rem = end - b;
    if (rem > 0) {                                   // one masked tail batch
        int ei = b + slot;
        int eidx = (ei < end) ? ei : end - 1;        // clamp: dup line, no new miss
        int s = csr_src[eidx];
        uint4 v = *(const uint4*)(ybase + (((unsigned)s << 7) + fb16));
        if (slot < rem) add_unpack2(acc2, v);
    }

    float acc[8] = {acc2[0].x, acc2[0].y, acc2[1].x, acc2[1].y,
                    acc2[2].x, acc2[2].y, acc2[3].x, acc2[3].y};

    // sum the 8 slots: xor over slot bits
    #pragma unroll
    for (int m = 8; m <= 32; m <<= 1) {
        #pragma unroll
        for (int i = 0; i < 8; ++i) acc[i] += __shfl_xor(acc[i], m, 64);
    }

    float dv = dinv[row];
    if (!FINAL) {
        if (slot == 0) {
            float s2 = dv * dv;
            union { ushort_t us[8]; uint4 u; } o;
            #pragma unroll
            for (int i = 0; i < 8; ++i) o.us[i] = f2bf(acc[i] * s2);
            *(uint4*)(yout + (size_t)row * DOUT + fb * 8) = o.u;
        }
    } else {
        const float4* bp = (const float4*)(bias + fb * 8);
        float4 b0 = bp[0], b1 = bp[1];
        float e[8];
        e[0] = dv * acc[0] + b0.x; e[1] = dv * acc[1] + b0.y;
        e[2] = dv * acc[2] + b0.z; e[3] = dv * acc[3] + b0.w;
        e[4] = dv * acc[4] + b1.x; e[5] = dv * acc[5] + b1.y;
        e[6] = dv * acc[6] + b1.z; e[7] = dv * acc[7] + b1.w;
        float m = e[0];
        #pragma unroll
        for (int i = 1; i < 8; ++i) m = fmaxf(m, e[i]);
        #pragma unroll
        for (int o2 = 1; o2 <= 4; o2 <<= 1) m = fmaxf(m, __shfl_xor(m, o2, 64));
        float ss = 0.f;
        #pragma unroll
        for (int i = 0; i < 8; ++i) ss += expf(e[i] - m);
        #pragma unroll
        for (int o2 = 1; o2 <= 4; o2 <<= 1) ss += __shfl_xor(ss, o2, 64);
        float lg = m + logf(ss);
        if (slot == 0) {
            float4* ep = (float4*)(emb + (size_t)row * DOUT + fb * 8);
            ep[0] = make_float4(e[0], e[1], e[2], e[3]);
            ep[1] = make_float4(e[4], e[5], e[6], e[7]);
            float4* op = (float4*)(out + (size_t)row * DOUT + fb * 8);
            op[0] = make_float4(e[0] - lg, e[1] - lg, e[2] - lg, e[3] - lg);
            op[1] = make_float4(e[4] - lg, e[5] - lg, e[6] - lg, e[7] - lg);
        }
    }
}

extern "C" void kernel_launch(void* const* d_in, const int* in_sizes, int n_in,
                              void* d_out, int out_size, void* d_ws, size_t ws_size,
                              hipStream_t stream) {
    const float* x    = (const float*)d_in[0];
    const int*   edge = (const int*)d_in[1];
    const float* W    = (const float*)d_in[2];
    const float* b    = (const float*)d_in[3];

    const int N = in_sizes[0] / DIN;   // 100000
    const int E = in_sizes[1] / 2;     // 1600000
    const int* src = edge;
    const int* dst = edge + E;

    float* out_ptr = (float*)d_out;                // [N,64] log_softmax
    float* emb_ptr = out_ptr + (size_t)N * DOUT;   // [N,64] emb

    const int B = (N + (1 << SH) - 1) >> SH;       // 391 buckets

    // workspace (~33 MB):
    //   cursor[512] | WT[8192] | row_ptr[N+1] | dinv[N] | csr_src[E+64] |
    //   arena: binned[B*CAP] ints (CSR build) aliased with y0b,y1b bf16 (gathers)
    int*     cursor      = (int*)d_ws;
    float*   WT          = (float*)(cursor + BMAX);
    int*     row_ptr     = (int*)(WT + DIN * DOUT);
    float*   dinv        = (float*)(row_ptr + N + 1);
    int*     csr_src     = (int*)(dinv + N);
    int*     arena       = csr_src + E + 64;        // +64: clamped tail-group loads
    int*     binned      = arena;
    ushort_t* y0b        = (ushort_t*)arena;        // aliases binned (dead after csr_kernel)
    ushort_t* y1b        = y0b + (size_t)N * DOUT;

    // 1. CSR by dst + dinv (scan inlined in csr_kernel); also W -> WT transpose
    init_cursor_kernel<<<8, 256, 0, stream>>>(cursor, csr_src + E, W, WT);
    bin_kernel<<<(E + 4095) / 4096, 256, 0, stream>>>(src, dst, cursor, binned, E, B);
    csr_kernel<<<B, 256, 0, stream>>>(binned, cursor, row_ptr, dinv, csr_src, N);

    // 2. project + pre-scale: y0' = dinv * (x @ W^T)   (bf16)
    gemm_kernel<<<(N + XROWS - 1) / XROWS, 256, 0, stream>>>(x, WT, dinv, y0b, N);

    // 3. hop 1: y1' = dinv^2 * (y0'[row] + sum y0'[src])
    gather_kernel<0><<<(N + 3) / 4, 256, 0, stream>>>(row_ptr, csr_src, dinv, y0b, b,
                                                      y1b, nullptr, nullptr, N);

    // 4. hop 2 + bias + log_softmax, fused
    gather_kernel<1><<<(N + 3) / 4, 256, 0, stream>>>(row_ptr, csr_src, dinv, y1b, b,
                                                      nullptr, out_ptr, emb_ptr, N);
}

// Round 12
// 198.043 us; speedup vs baseline: 1.2809x; 1.0273x over previous
//
#include <hip/hip_runtime.h>

#define DIN 128
#define DOUT 64
#define SH 8            // nodes per bucket = 256
#define CAP 8192        // slots per bucket (avg ~4096, +64 sigma headroom)
#define BMAX 512
#define XS_STRIDE (DIN + 4)
#define XROWS 32        // x tile rows (LDS 49.6KB total -> 3 blocks/CU)
#define BCHUNK 4096     // edges per bin block

typedef unsigned short ushort_t;
typedef float v2f __attribute__((ext_vector_type(2)));

__device__ __forceinline__ ushort_t f2bf(float f) {
    union { float f; unsigned u; } v; v.f = f;
    unsigned r = v.u + 0x7FFF + ((v.u >> 16) & 1);   // round-nearest-even
    return (ushort_t)(r >> 16);
}

// ---------- pass A: bin edges by dst>>SH, packed (ldst<<17)|src ----------
// dst chunk staged in LDS: global dst read once instead of twice.
__global__ __launch_bounds__(256) void bin_kernel(const int* __restrict__ src,
                                                  const int* __restrict__ dst,
                                                  int* __restrict__ cursor,
                                                  int* __restrict__ binned, int E, int B) {
    __shared__ int hist_s[BMAX], gbase_s[BMAX], cur_s[BMAX];
    __shared__ int dst_s[BCHUNK];                 // 16 KB
    for (int i = threadIdx.x; i < B; i += 256) { hist_s[i] = 0; cur_s[i] = 0; }
    __syncthreads();
    int e0 = blockIdx.x * BCHUNK;
    int e1 = min(e0 + BCHUNK, E);
    int n  = e1 - e0;
    for (int i = threadIdx.x; i < n; i += 256) {
        int d = dst[e0 + i];
        dst_s[i] = d;
        atomicAdd(&hist_s[d >> SH], 1);
    }
    __syncthreads();
    for (int b = threadIdx.x; b < B; b += 256) {
        int h = hist_s[b];
        gbase_s[b] = h ? atomicAdd(&cursor[b], h) : 0;
    }
    __syncthreads();
    for (int i = threadIdx.x; i < n; i += 256) {
        int d = dst_s[i], s = src[e0 + i];
        int b = d >> SH;
        int off  = atomicAdd(&cur_s[b], 1);
        int slot = gbase_s[b] + off;
        if (slot < (b + 1) * CAP)
            binned[slot] = ((d & ((1 << SH) - 1)) << 17) | s;
    }
}

// init ALL BMAX cursors + zero csr pad + transpose W -> WT [128][64]
__global__ void init_cursor_kernel(int* cursor, int* csr_pad,
                                   const float* __restrict__ W, float* __restrict__ WT) {
    int b = blockIdx.x * 256 + threadIdx.x;
    if (b < BMAX) cursor[b] = b * CAP;
    if (b < 64) csr_pad[b] = 0;
    for (int j = b; j < DIN * DOUT; j += 2048)
        WT[j] = W[(j & 63) * DIN + (j >> 6)];
}

// ---------- pass B: per-bucket CSR build + inline bucket scan + row_ptr + dinv ----------
__global__ __launch_bounds__(256) void csr_kernel(const int* __restrict__ binned,
                                                  const int* __restrict__ cursor,
                                                  int* __restrict__ row_ptr,
                                                  float* __restrict__ dinv,
                                                  int* __restrict__ csr_src, int N) {
    __shared__ int cnt_s[256], off_s[256], bsc[BMAX];
    int b = blockIdx.x;
    int t = threadIdx.x;

    // inline exclusive scan over all bucket counts (each block redundantly, LDS)
    int c0 = cursor[t] - t * CAP;                 if (c0 > CAP) c0 = CAP;
    int c1 = cursor[t + 256] - (t + 256) * CAP;   if (c1 > CAP) c1 = CAP;
    bsc[t] = c0; bsc[t + 256] = c1;
    __syncthreads();
    for (int off = 1; off < BMAX; off <<= 1) {
        int v0 = (t >= off) ? bsc[t - off] : 0;
        int v1 = (t + 256 >= off) ? bsc[t + 256 - off] : 0;
        __syncthreads();
        bsc[t] += v0; bsc[t + 256] += v1;
        __syncthreads();
    }
    int cb = cursor[b] - b * CAP; if (cb > CAP) cb = CAP;   // this bucket's count
    int base = bsc[b] - cb;                                  // exclusive prefix
    int ecnt = cb;
    const int* eb = binned + (size_t)b * CAP;

    cnt_s[t] = 0;
    __syncthreads();
    for (int i = t; i < ecnt; i += 256)
        atomicAdd(&cnt_s[eb[i] >> 17], 1);
    __syncthreads();
    int myc = cnt_s[t];
    off_s[t] = myc;
    __syncthreads();
    for (int off = 1; off < 256; off <<= 1) {
        int v = (t >= off) ? off_s[t - off] : 0;
        __syncthreads();
        off_s[t] += v;
        __syncthreads();
    }
    int excl = off_s[t] - myc;
    int node = (b << SH) + t;
    if (node < N) {
        row_ptr[node] = base + excl;
        dinv[node] = rsqrtf((float)myc + 1.0f);  // +1 = self loop
        if (node == N - 1) row_ptr[N] = base + excl + myc;   // sentinel == E
    }
    __syncthreads();
    off_s[t] = base + excl;   // global write cursor for this node
    __syncthreads();
    for (int i = t; i < ecnt; i += 256) {
        int p = eb[i];
        int slot = atomicAdd(&off_s[p >> 17], 1);
        csr_src[slot] = p & 0x1FFFF;
    }
}

// ---------- projection: y0' = dinv * (x @ W^T), stored bf16 ----------
__global__ __launch_bounds__(256) void gemm_kernel(const float* __restrict__ x,
                                                   const float* __restrict__ WT,
                                                   const float* __restrict__ dinv,
                                                   ushort_t* __restrict__ yb, int N) {
    __shared__ float Ws[DIN * DOUT];              // 32 KB, [k][o] (already transposed)
    __shared__ float xs[XROWS * XS_STRIDE];       // 16.9 KB
    int tid  = threadIdx.x;
    int row0 = blockIdx.x * XROWS;

    {
        const float4* s4 = (const float4*)WT;
        float4* d4 = (float4*)Ws;
        for (int j = tid; j < DIN * DOUT / 4; j += 256) d4[j] = s4[j];
    }
    for (int j = tid; j < XROWS * DIN / 4; j += 256) {
        int r  = j >> 5;
        int c4 = (j & 31) * 4;
        int grow = row0 + r;
        float4 v = {0.f, 0.f, 0.f, 0.f};
        if (grow < N) v = *(const float4*)&x[(size_t)grow * DIN + c4];
        *(float4*)&xs[r * XS_STRIDE + c4] = v;
    }
    __syncthreads();

    int g  = tid & 15;
    int rg = tid >> 4;
    int r0 = rg * 2;

    float4 acc0 = {}, acc1 = {};
    for (int kk = 0; kk < DIN; kk += 4) {
        float4 wv0 = *(const float4*)&Ws[(kk + 0) * DOUT + g * 4];
        float4 wv1 = *(const float4*)&Ws[(kk + 1) * DOUT + g * 4];
        float4 wv2 = *(const float4*)&Ws[(kk + 2) * DOUT + g * 4];
        float4 wv3 = *(const float4*)&Ws[(kk + 3) * DOUT + g * 4];
        float4 xv0 = *(const float4*)&xs[(r0 + 0) * XS_STRIDE + kk];
        float4 xv1 = *(const float4*)&xs[(r0 + 1) * XS_STRIDE + kk];
        acc0.x += xv0.x * wv0.x + xv0.y * wv1.x + xv0.z * wv2.x + xv0.w * wv3.x;
        acc0.y += xv0.x * wv0.y + xv0.y * wv1.y + xv0.z * wv2.y + xv0.w * wv3.y;
        acc0.z += xv0.x * wv0.z + xv0.y * wv1.z + xv0.z * wv2.z + xv0.w * wv3.z;
        acc0.w += xv0.x * wv0.w + xv0.y * wv1.w + xv0.z * wv2.w + xv0.w * wv3.w;
        acc1.x += xv1.x * wv0.x + xv1.y * wv1.x + xv1.z * wv2.x + xv1.w * wv3.x;
        acc1.y += xv1.x * wv0.y + xv1.y * wv1.y + xv1.z * wv2.y + xv1.w * wv3.y;
        acc1.z += xv1.x * wv0.z + xv1.y * wv1.z + xv1.z * wv2.z + xv1.w * wv3.z;
        acc1.w += xv1.x * wv0.w + xv1.y * wv1.w + xv1.z * wv2.w + xv1.w * wv3.w;
    }
    #pragma unroll
    for (int r = 0; r < 2; ++r) {
        int grow = row0 + r0 + r;
        if (grow < N) {
            float dv = dinv[grow];
            float4 a = r ? acc1 : acc0;
            ushort4 o;
            o.x = f2bf(a.x * dv); o.y = f2bf(a.y * dv);
            o.z = f2bf(a.z * dv); o.w = f2bf(a.w * dv);
            *(ushort4*)&yb[(size_t)grow * DOUT + g * 4] = o;
        }
    }
}

// unpack 4 dwords (8 bf16) and add into v2f acc pairs (v_pk_add_f32)
__device__ __forceinline__ void add_unpack2(v2f* acc, uint4 v) {
    unsigned u[4] = {v.x, v.y, v.z, v.w};
    #pragma unroll
    for (int d = 0; d < 4; ++d) {
        union { unsigned u; float f; } lo, hi;
        lo.u = u[d] << 16;
        hi.u = u[d] & 0xFFFF0000u;
        v2f p; p.x = lo.f; p.y = hi.f;
        acc[d] += p;
    }
}

// ---------- wide pull-gather: wave = 8 slots x 8 fb ----------
template <int FINAL>
__global__ __launch_bounds__(256) void gather_kernel(const int* __restrict__ row_ptr,
                                                     const int* __restrict__ csr_src,
                                                     const float* __restrict__ dinv,
                                                     const ushort_t* __restrict__ yin,
                                                     const float* __restrict__ bias,
                                                     ushort_t* __restrict__ yout,
                                                     float* __restrict__ out,
                                                     float* __restrict__ emb, int N) {
    int row = blockIdx.x * 4 + (threadIdx.x >> 6);
    if (row >= N) return;
    int lane = threadIdx.x & 63;
    int fb   = lane & 7;    // feature block: features [fb*8, fb*8+8)
    int slot = lane >> 3;   // edge slot within a batch of 8
    int start = __builtin_amdgcn_readfirstlane(row_ptr[row]);
    int end   = __builtin_amdgcn_readfirstlane(row_ptr[row + 1]);

    const char* ybase = (const char*)yin;
    unsigned fb16 = (unsigned)fb * 16u;

    v2f acc2[4] = {};

    // self loop: all lanes load row's fb-block, slot 0 accumulates
    {
        uint4 sv = *(const uint4*)(ybase + (((unsigned)row << 7) + fb16));
        if (slot == 0) add_unpack2(acc2, sv);
    }

    int b = start;
    int nfull = (end - start) >> 3;
    for (int i = 0; i < nfull; ++i, b += 8) {        // unmasked full batches
        int s = csr_src[b + slot];                   // 32B span per batch
        uint4 v = *(const uint4*)(ybase + (((unsigned)s << 7) + fb16));
        add_unpack2(acc2, v);
    }
    int rem = end - b;
    if (rem > 0) {                                   // one masked tail batch
        int ei = b + slot;
        int eidx = (ei < end) ? ei : end - 1;        // clamp: dup line, no new miss
        int s = csr_src[eidx];
        uint4 v = *(const uint4*)(ybase + (((unsigned)s << 7) + fb16));
        if (slot < rem) add_unpack2(acc2, v);
    }

    float acc[8] = {acc2[0].x, acc2[0].y, acc2[1].x, acc2[1].y,
                    acc2[2].x, acc2[2].y, acc2[3].x, acc2[3].y};

    // sum the 8 slots: xor over slot bits
    #pragma unroll
    for (int m = 8; m <= 32; m <<= 1) {
        #pragma unroll
        for (int i = 0; i < 8; ++i) acc[i] += __shfl_xor(acc[i], m, 64);
    }

    float dv = dinv[row];
    if (!FINAL) {
        if (slot == 0) {
            float s2 = dv * dv;
            union { ushort_t us[8]; uint4 u; } o;
            #pragma unroll
            for (int i = 0; i < 8; ++i) o.us[i] = f2bf(acc[i] * s2);
            *(uint4*)(yout + (size_t)row * DOUT + fb * 8) = o.u;
        }
    } else {
        const float4* bp = (const float4*)(bias + fb * 8);
        float4 b0 = bp[0], b1 = bp[1];
        float e[8];
        e[0] = dv * acc[0] + b0.x; e[1] = dv * acc[1] + b0.y;
        e[2] = dv * acc[2] + b0.z; e[3] = dv * acc[3] + b0.w;
        e[4] = dv * acc[4] + b1.x; e[5] = dv * acc[5] + b1.y;
        e[6] = dv * acc[6] + b1.z; e[7] = dv * acc[7] + b1.w;
        float m = e[0];
        #pragma unroll
        for (int i = 1; i < 8; ++i) m = fmaxf(m, e[i]);
        #pragma unroll
        for (int o2 = 1; o2 <= 4; o2 <<= 1) m = fmaxf(m, __shfl_xor(m, o2, 64));
        float ss = 0.f;
        #pragma unroll
        for (int i = 0; i < 8; ++i) ss += __expf(e[i] - m);   // fast exp (2-3 insts)
        #pragma unroll
        for (int o2 = 1; o2 <= 4; o2 <<= 1) ss += __shfl_xor(ss, o2, 64);
        float lg = m + __logf(ss);                             // fast log
        if (slot == 0) {
            float4* ep = (float4*)(emb + (size_t)row * DOUT + fb * 8);
            ep[0] = make_float4(e[0], e[1], e[2], e[3]);
            ep[1] = make_float4(e[4], e[5], e[6], e[7]);
            float4* op = (float4*)(out + (size_t)row * DOUT + fb * 8);
            op[0] = make_float4(e[0] - lg, e[1] - lg, e[2] - lg, e[3] - lg);
            op[1] = make_float4(e[4] - lg, e[5] - lg, e[6] - lg, e[7] - lg);
        }
    }
}

extern "C" void kernel_launch(void* const* d_in, const int* in_sizes, int n_in,
                              void* d_out, int out_size, void* d_ws, size_t ws_size,
                              hipStream_t stream) {
    const float* x    = (const float*)d_in[0];
    const int*   edge = (const int*)d_in[1];
    const float* W    = (const float*)d_in[2];
    const float* b    = (const float*)d_in[3];

    const int N = in_sizes[0] / DIN;   // 100000
    const int E = in_sizes[1] / 2;     // 1600000
    const int* src = edge;
    const int* dst = edge + E;

    float* out_ptr = (float*)d_out;                // [N,64] log_softmax
    float* emb_ptr = out_ptr + (size_t)N * DOUT;   // [N,64] emb

    const int B = (N + (1 << SH) - 1) >> SH;       // 391 buckets

    // workspace (~33 MB):
    //   cursor[512] | WT[8192] | row_ptr[N+1] | dinv[N] | csr_src[E+64] |
    //   arena: binned[B*CAP] ints (CSR build) aliased with y0b,y1b bf16 (gathers)
    int*     cursor      = (int*)d_ws;
    float*   WT          = (float*)(cursor + BMAX);
    int*     row_ptr     = (int*)(WT + DIN * DOUT);
    float*   dinv        = (float*)(row_ptr + N + 1);
    int*     csr_src     = (int*)(dinv + N);
    int*     arena       = csr_src + E + 64;        // +64: clamped tail-group loads
    int*     binned      = arena;
    ushort_t* y0b        = (ushort_t*)arena;        // aliases binned (dead after csr_kernel)
    ushort_t* y1b        = y0b + (size_t)N * DOUT;

    // 1. CSR by dst + dinv (scan inlined in csr_kernel); also W -> WT transpose
    init_cursor_kernel<<<8, 256, 0, stream>>>(cursor, csr_src + E, W, WT);
    bin_kernel<<<(E + BCHUNK - 1) / BCHUNK, 256, 0, stream>>>(src, dst, cursor, binned, E, B);
    csr_kernel<<<B, 256, 0, stream>>>(binned, cursor, row_ptr, dinv, csr_src, N);

    // 2. project + pre-scale: y0' = dinv * (x @ W^T)   (bf16)
    gemm_kernel<<<(N + XROWS - 1) / XROWS, 256, 0, stream>>>(x, WT, dinv, y0b, N);

    // 3. hop 1: y1' = dinv^2 * (y0'[row] + sum y0'[src])
    gather_kernel<0><<<(N + 3) / 4, 256, 0, stream>>>(row_ptr, csr_src, dinv, y0b, b,
                                                      y1b, nullptr, nullptr, N);

    // 4. hop 2 + bias + log_softmax, fused
    gather_kernel<1><<<(N + 3) / 4, 256, 0, stream>>>(row_ptr, csr_src, dinv, y1b, b,
                                                      nullptr, out_ptr, emb_ptr, N);
}

// Round 13
// 192.364 us; speedup vs baseline: 1.3187x; 1.0295x over previous
//
#include <hip/hip_runtime.h>

#define DIN 128
#define DOUT 64
#define SH 8            // nodes per bucket = 256
#define CAP 8192        // slots per bucket (avg ~4096, +64 sigma headroom)
#define BMAX 512
#define XS_STRIDE (DIN + 4)
#define XROWS 32        // x tile rows (LDS 49.6KB total -> 3 blocks/CU)
#define BCHUNK 4096     // edges per bin block

typedef unsigned short ushort_t;
typedef float v2f __attribute__((ext_vector_type(2)));

__device__ __forceinline__ ushort_t f2bf(float f) {
    union { float f; unsigned u; } v; v.f = f;
    unsigned r = v.u + 0x7FFF + ((v.u >> 16) & 1);   // round-nearest-even
    return (ushort_t)(r >> 16);
}

// ---------- pass A: bin edges by dst>>SH, packed (ldst<<17)|src ----------
// dst chunk staged in LDS; cursor is zero-initialized (relative bases).
__global__ __launch_bounds__(256) void bin_kernel(const int* __restrict__ src,
                                                  const int* __restrict__ dst,
                                                  int* __restrict__ cursor,
                                                  int* __restrict__ binned, int E, int B) {
    __shared__ int hist_s[BMAX], gbase_s[BMAX], cur_s[BMAX];
    __shared__ int dst_s[BCHUNK];                 // 16 KB
    for (int i = threadIdx.x; i < B; i += 256) { hist_s[i] = 0; cur_s[i] = 0; }
    __syncthreads();
    int e0 = blockIdx.x * BCHUNK;
    int e1 = min(e0 + BCHUNK, E);
    int n  = e1 - e0;
    for (int i = threadIdx.x; i < n; i += 256) {
        int d = dst[e0 + i];
        dst_s[i] = d;
        atomicAdd(&hist_s[d >> SH], 1);
    }
    __syncthreads();
    for (int b = threadIdx.x; b < B; b += 256) {
        int h = hist_s[b];
        gbase_s[b] = h ? atomicAdd(&cursor[b], h) : 0;   // relative base (cursor starts 0)
    }
    __syncthreads();
    for (int i = threadIdx.x; i < n; i += 256) {
        int d = dst_s[i], s = src[e0 + i];
        int b = d >> SH;
        int off = atomicAdd(&cur_s[b], 1);
        int rel = gbase_s[b] + off;
        if (rel < CAP)
            binned[b * CAP + rel] = ((d & ((1 << SH) - 1)) << 17) | s;
    }
}

// zero csr pad + transpose W -> WT [128][64]
__global__ void init_kernel(int* csr_pad, const float* __restrict__ W,
                            float* __restrict__ WT) {
    int b = blockIdx.x * 256 + threadIdx.x;
    if (b < 64) csr_pad[b] = 0;
    for (int j = b; j < DIN * DOUT; j += 2048)
        WT[j] = W[(j & 63) * DIN + (j >> 6)];
}

// ---------- pass B: per-bucket CSR build (bucket staged in LDS) ----------
__global__ __launch_bounds__(256) void csr_kernel(const int* __restrict__ binned,
                                                  const int* __restrict__ cursor,
                                                  int* __restrict__ row_ptr,
                                                  float* __restrict__ dinv,
                                                  int* __restrict__ csr_src, int N) {
    __shared__ int cnt_s[256], off_s[256], bsc[BMAX];
    __shared__ int eb_s[CAP];                     // 32 KB bucket stage
    int b = blockIdx.x;
    int t = threadIdx.x;

    // inline exclusive scan over all bucket counts (each block redundantly, LDS)
    int c0 = min(cursor[t], CAP);
    int c1 = min(cursor[t + 256], CAP);
    bsc[t] = c0; bsc[t + 256] = c1;
    __syncthreads();
    for (int off = 1; off < BMAX; off <<= 1) {
        int v0 = (t >= off) ? bsc[t - off] : 0;
        int v1 = (t + 256 >= off) ? bsc[t + 256 - off] : 0;
        __syncthreads();
        bsc[t] += v0; bsc[t + 256] += v1;
        __syncthreads();
    }
    int cb = min(cursor[b], CAP);                 // this bucket's count
    int base = bsc[b] - cb;                       // exclusive prefix
    int ecnt = cb;
    const int* eb = binned + (size_t)b * CAP;

    cnt_s[t] = 0;
    __syncthreads();
    // stage bucket into LDS + histogram in one pass
    for (int i = t; i < ecnt; i += 256) {
        int p = eb[i];
        eb_s[i] = p;
        atomicAdd(&cnt_s[p >> 17], 1);
    }
    __syncthreads();
    int myc = cnt_s[t];
    off_s[t] = myc;
    __syncthreads();
    for (int off = 1; off < 256; off <<= 1) {
        int v = (t >= off) ? off_s[t - off] : 0;
        __syncthreads();
        off_s[t] += v;
        __syncthreads();
    }
    int excl = off_s[t] - myc;
    int node = (b << SH) + t;
    if (node < N) {
        row_ptr[node] = base + excl;
        dinv[node] = rsqrtf((float)myc + 1.0f);   // +1 = self loop
        if (node == N - 1) row_ptr[N] = base + excl + myc;   // sentinel == E
    }
    __syncthreads();
    off_s[t] = base + excl;   // global write cursor for this node
    __syncthreads();
    for (int i = t; i < ecnt; i += 256) {
        int p = eb_s[i];
        int slot = atomicAdd(&off_s[p >> 17], 1);
        csr_src[slot] = p & 0x1FFFF;
    }
}

// ---------- projection: y0' = dinv * (x @ W^T), stored bf16 ----------
__global__ __launch_bounds__(256) void gemm_kernel(const float* __restrict__ x,
                                                   const float* __restrict__ WT,
                                                   const float* __restrict__ dinv,
                                                   ushort_t* __restrict__ yb, int N) {
    __shared__ float Ws[DIN * DOUT];              // 32 KB, [k][o] (already transposed)
    __shared__ float xs[XROWS * XS_STRIDE];       // 16.9 KB
    int tid  = threadIdx.x;
    int row0 = blockIdx.x * XROWS;

    {
        const float4* s4 = (const float4*)WT;
        float4* d4 = (float4*)Ws;
        for (int j = tid; j < DIN * DOUT / 4; j += 256) d4[j] = s4[j];
    }
    for (int j = tid; j < XROWS * DIN / 4; j += 256) {
        int r  = j >> 5;
        int c4 = (j & 31) * 4;
        int grow = row0 + r;
        float4 v = {0.f, 0.f, 0.f, 0.f};
        if (grow < N) v = *(const float4*)&x[(size_t)grow * DIN + c4];
        *(float4*)&xs[r * XS_STRIDE + c4] = v;
    }
    __syncthreads();

    int g  = tid & 15;
    int rg = tid >> 4;
    int r0 = rg * 2;

    float4 acc0 = {}, acc1 = {};
    for (int kk = 0; kk < DIN; kk += 4) {
        float4 wv0 = *(const float4*)&Ws[(kk + 0) * DOUT + g * 4];
        float4 wv1 = *(const float4*)&Ws[(kk + 1) * DOUT + g * 4];
        float4 wv2 = *(const float4*)&Ws[(kk + 2) * DOUT + g * 4];
        float4 wv3 = *(const float4*)&Ws[(kk + 3) * DOUT + g * 4];
        float4 xv0 = *(const float4*)&xs[(r0 + 0) * XS_STRIDE + kk];
        float4 xv1 = *(const float4*)&xs[(r0 + 1) * XS_STRIDE + kk];
        acc0.x += xv0.x * wv0.x + xv0.y * wv1.x + xv0.z * wv2.x + xv0.w * wv3.x;
        acc0.y += xv0.x * wv0.y + xv0.y * wv1.y + xv0.z * wv2.y + xv0.w * wv3.y;
        acc0.z += xv0.x * wv0.z + xv0.y * wv1.z + xv0.z * wv2.z + xv0.w * wv3.z;
        acc0.w += xv0.x * wv0.w + xv0.y * wv1.w + xv0.z * wv2.w + xv0.w * wv3.w;
        acc1.x += xv1.x * wv0.x + xv1.y * wv1.x + xv1.z * wv2.x + xv1.w * wv3.x;
        acc1.y += xv1.x * wv0.y + xv1.y * wv1.y + xv1.z * wv2.y + xv1.w * wv3.y;
        acc1.z += xv1.x * wv0.z + xv1.y * wv1.z + xv1.z * wv2.z + xv1.w * wv3.z;
        acc1.w += xv1.x * wv0.w + xv1.y * wv1.w + xv1.z * wv2.w + xv1.w * wv3.w;
    }
    #pragma unroll
    for (int r = 0; r < 2; ++r) {
        int grow = row0 + r0 + r;
        if (grow < N) {
            float dv = dinv[grow];
            float4 a = r ? acc1 : acc0;
            ushort4 o;
            o.x = f2bf(a.x * dv); o.y = f2bf(a.y * dv);
            o.z = f2bf(a.z * dv); o.w = f2bf(a.w * dv);
            *(ushort4*)&yb[(size_t)grow * DOUT + g * 4] = o;
        }
    }
}

// unpack 4 dwords (8 bf16) and add into v2f acc pairs (v_pk_add_f32)
__device__ __forceinline__ void add_unpack2(v2f* acc, uint4 v) {
    unsigned u[4] = {v.x, v.y, v.z, v.w};
    #pragma unroll
    for (int d = 0; d < 4; ++d) {
        union { unsigned u; float f; } lo, hi;
        lo.u = u[d] << 16;
        hi.u = u[d] & 0xFFFF0000u;
        v2f p; p.x = lo.f; p.y = hi.f;
        acc[d] += p;
    }
}

// ---------- wide pull-gather: wave = 8 slots x 8 fb; self fused into tail ----------
template <int FINAL>
__global__ __launch_bounds__(256) void gather_kernel(const int* __restrict__ row_ptr,
                                                     const int* __restrict__ csr_src,
                                                     const float* __restrict__ dinv,
                                                     const ushort_t* __restrict__ yin,
                                                     const float* __restrict__ bias,
                                                     ushort_t* __restrict__ yout,
                                                     float* __restrict__ out,
                                                     float* __restrict__ emb, int N) {
    int row = blockIdx.x * 4 + (threadIdx.x >> 6);
    if (row >= N) return;
    int lane = threadIdx.x & 63;
    int fb   = lane & 7;    // feature block: features [fb*8, fb*8+8)
    int slot = lane >> 3;   // edge slot within a batch of 8
    int start = __builtin_amdgcn_readfirstlane(row_ptr[row]);
    int end   = __builtin_amdgcn_readfirstlane(row_ptr[row + 1]);

    const char* ybase = (const char*)yin;
    unsigned fb16 = (unsigned)fb * 16u;

    v2f acc2[4] = {};

    int b = start;
    int deg = end - start;
    int nfull = deg >> 3;
    #pragma unroll 2
    for (int i = 0; i < nfull; ++i, b += 8) {        // unmasked full batches
        int s = csr_src[b + slot];                   // 32B span per batch
        uint4 v = *(const uint4*)(ybase + (((unsigned)s << 7) + fb16));
        add_unpack2(acc2, v);
    }
    // tail batch: rem edges in slots [0,rem), SELF LOOP in slot rem
    {
        int rem = deg & 7;
        int s = (slot < rem) ? csr_src[b + slot] : row;   // pad-safe (csr pad >= 8)
        uint4 v = *(const uint4*)(ybase + (((unsigned)s << 7) + fb16));
        if (slot <= rem) add_unpack2(acc2, v);
    }

    float acc[8] = {acc2[0].x, acc2[0].y, acc2[1].x, acc2[1].y,
                    acc2[2].x, acc2[2].y, acc2[3].x, acc2[3].y};

    // sum the 8 slots: xor over slot bits
    #pragma unroll
    for (int m = 8; m <= 32; m <<= 1) {
        #pragma unroll
        for (int i = 0; i < 8; ++i) acc[i] += __shfl_xor(acc[i], m, 64);
    }

    float dv = dinv[row];
    if (!FINAL) {
        if (slot == 0) {
            float s2 = dv * dv;
            union { ushort_t us[8]; uint4 u; } o;
            #pragma unroll
            for (int i = 0; i < 8; ++i) o.us[i] = f2bf(acc[i] * s2);
            *(uint4*)(yout + (size_t)row * DOUT + fb * 8) = o.u;
        }
    } else {
        const float4* bp = (const float4*)(bias + fb * 8);
        float4 b0 = bp[0], b1 = bp[1];
        float e[8];
        e[0] = dv * acc[0] + b0.x; e[1] = dv * acc[1] + b0.y;
        e[2] = dv * acc[2] + b0.z; e[3] = dv * acc[3] + b0.w;
        e[4] = dv * acc[4] + b1.x; e[5] = dv * acc[5] + b1.y;
        e[6] = dv * acc[6] + b1.z; e[7] = dv * acc[7] + b1.w;
        float m = e[0];
        #pragma unroll
        for (int i = 1; i < 8; ++i) m = fmaxf(m, e[i]);
        #pragma unroll
        for (int o2 = 1; o2 <= 4; o2 <<= 1) m = fmaxf(m, __shfl_xor(m, o2, 64));
        float ss = 0.f;
        #pragma unroll
        for (int i = 0; i < 8; ++i) ss += __expf(e[i] - m);   // fast exp
        #pragma unroll
        for (int o2 = 1; o2 <= 4; o2 <<= 1) ss += __shfl_xor(ss, o2, 64);
        float lg = m + __logf(ss);                             // fast log
        if (slot == 0) {
            float4* ep = (float4*)(emb + (size_t)row * DOUT + fb * 8);
            ep[0] = make_float4(e[0], e[1], e[2], e[3]);
            ep[1] = make_float4(e[4], e[5], e[6], e[7]);
            float4* op = (float4*)(out + (size_t)row * DOUT + fb * 8);
            op[0] = make_float4(e[0] - lg, e[1] - lg, e[2] - lg, e[3] - lg);
            op[1] = make_float4(e[4] - lg, e[5] - lg, e[6] - lg, e[7] - lg);
        }
    }
}

extern "C" void kernel_launch(void* const* d_in, const int* in_sizes, int n_in,
                              void* d_out, int out_size, void* d_ws, size_t ws_size,
                              hipStream_t stream) {
    const float* x    = (const float*)d_in[0];
    const int*   edge = (const int*)d_in[1];
    const float* W    = (const float*)d_in[2];
    const float* b    = (const float*)d_in[3];

    const int N = in_sizes[0] / DIN;   // 100000
    const int E = in_sizes[1] / 2;     // 1600000
    const int* src = edge;
    const int* dst = edge + E;

    float* out_ptr = (float*)d_out;                // [N,64] log_softmax
    float* emb_ptr = out_ptr + (size_t)N * DOUT;   // [N,64] emb

    const int B = (N + (1 << SH) - 1) >> SH;       // 391 buckets

    // workspace (~33 MB):
    //   cursor[512] | WT[8192] | row_ptr[N+1] | dinv[N] | csr_src[E+64] |
    //   arena: binned[B*CAP] ints (CSR build) aliased with y0b,y1b bf16 (gathers)
    int*     cursor      = (int*)d_ws;
    float*   WT          = (float*)(cursor + BMAX);
    int*     row_ptr     = (int*)(WT + DIN * DOUT);
    float*   dinv        = (float*)(row_ptr + N + 1);
    int*     csr_src     = (int*)(dinv + N);
    int*     arena       = csr_src + E + 64;        // +64: tail/pad loads
    int*     binned      = arena;
    ushort_t* y0b        = (ushort_t*)arena;        // aliases binned (dead after csr_kernel)
    ushort_t* y1b        = y0b + (size_t)N * DOUT;

    // 1. CSR by dst + dinv; W -> WT transpose
    hipMemsetAsync(cursor, 0, BMAX * sizeof(int), stream);
    init_kernel<<<8, 256, 0, stream>>>(csr_src + E, W, WT);
    bin_kernel<<<(E + BCHUNK - 1) / BCHUNK, 256, 0, stream>>>(src, dst, cursor, binned, E, B);
    csr_kernel<<<B, 256, 0, stream>>>(binned, cursor, row_ptr, dinv, csr_src, N);

    // 2. project + pre-scale: y0' = dinv * (x @ W^T)   (bf16)
    gemm_kernel<<<(N + XROWS - 1) / XROWS, 256, 0, stream>>>(x, WT, dinv, y0b, N);

    // 3. hop 1: y1' = dinv^2 * (y0'[row] + sum y0'[src])
    gather_kernel<0><<<(N + 3) / 4, 256, 0, stream>>>(row_ptr, csr_src, dinv, y0b, b,
                                                      y1b, nullptr, nullptr, N);

    // 4. hop 2 + bias + log_softmax, fused
    gather_kernel<1><<<(N + 3) / 4, 256, 0, stream>>>(row_ptr, csr_src, dinv, y1b, b,
                                                      nullptr, out_ptr, emb_ptr, N);
}

// Round 14
// 192.159 us; speedup vs baseline: 1.3201x; 1.0011x over previous
//
#include <hip/hip_runtime.h>

#define DIN 128
#define DOUT 64
#define SH 8            // nodes per bucket = 256
#define CAP 8192        // slots per bucket (avg ~4096, +64 sigma headroom)
#define BMAX 512
#define XS_STRIDE (DIN + 4)
#define XROWS 32        // x tile rows (LDS 49.6KB total -> 3 blocks/CU)
#define BCHUNK 4096     // edges per bin block

typedef unsigned short ushort_t;
typedef float v2f __attribute__((ext_vector_type(2)));

__device__ __forceinline__ ushort_t f2bf(float f) {
    union { float f; unsigned u; } v; v.f = f;
    unsigned r = v.u + 0x7FFF + ((v.u >> 16) & 1);   // round-nearest-even
    return (ushort_t)(r >> 16);
}

// ---------- pass A: bin edges by dst>>SH, packed (ldst<<17)|src ----------
__global__ __launch_bounds__(256) void bin_kernel(const int* __restrict__ src,
                                                  const int* __restrict__ dst,
                                                  int* __restrict__ cursor,
                                                  int* __restrict__ binned, int E, int B) {
    __shared__ int hist_s[BMAX], gbase_s[BMAX], cur_s[BMAX];
    __shared__ int dst_s[BCHUNK];                 // 16 KB
    for (int i = threadIdx.x; i < B; i += 256) { hist_s[i] = 0; cur_s[i] = 0; }
    __syncthreads();
    int e0 = blockIdx.x * BCHUNK;
    int e1 = min(e0 + BCHUNK, E);
    int n  = e1 - e0;
    for (int i = threadIdx.x; i < n; i += 256) {
        int d = dst[e0 + i];
        dst_s[i] = d;
        atomicAdd(&hist_s[d >> SH], 1);
    }
    __syncthreads();
    for (int b = threadIdx.x; b < B; b += 256) {
        int h = hist_s[b];
        gbase_s[b] = h ? atomicAdd(&cursor[b], h) : 0;   // relative base (cursor starts 0)
    }
    __syncthreads();
    for (int i = threadIdx.x; i < n; i += 256) {
        int d = dst_s[i], s = src[e0 + i];
        int b = d >> SH;
        int off = atomicAdd(&cur_s[b], 1);
        int rel = gbase_s[b] + off;
        if (rel < CAP)
            binned[b * CAP + rel] = ((d & ((1 << SH) - 1)) << 17) | s;
    }
}

// zero cursor + csr pad, transpose W -> WT [128][64]
__global__ void init_kernel(int* cursor, int* csr_pad, const float* __restrict__ W,
                            float* __restrict__ WT) {
    int b = blockIdx.x * 256 + threadIdx.x;
    if (b < BMAX) cursor[b] = 0;
    if (b < 64) csr_pad[b] = 0;
    for (int j = b; j < DIN * DOUT; j += 2048)
        WT[j] = W[(j & 63) * DIN + (j >> 6)];
}

// ---------- pass B: per-bucket CSR build (bucket staged in LDS) ----------
__global__ __launch_bounds__(256) void csr_kernel(const int* __restrict__ binned,
                                                  const int* __restrict__ cursor,
                                                  int* __restrict__ row_ptr,
                                                  float* __restrict__ dinv,
                                                  int* __restrict__ csr_src, int N) {
    __shared__ int cnt_s[256], off_s[256], bsc[BMAX];
    __shared__ int eb_s[CAP];                     // 32 KB bucket stage
    int b = blockIdx.x;
    int t = threadIdx.x;

    int c0 = min(cursor[t], CAP);
    int c1 = min(cursor[t + 256], CAP);
    bsc[t] = c0; bsc[t + 256] = c1;
    __syncthreads();
    for (int off = 1; off < BMAX; off <<= 1) {
        int v0 = (t >= off) ? bsc[t - off] : 0;
        int v1 = (t + 256 >= off) ? bsc[t + 256 - off] : 0;
        __syncthreads();
        bsc[t] += v0; bsc[t + 256] += v1;
        __syncthreads();
    }
    int cb = min(cursor[b], CAP);                 // this bucket's count
    int base = bsc[b] - cb;                       // exclusive prefix
    int ecnt = cb;
    const int* eb = binned + (size_t)b * CAP;

    cnt_s[t] = 0;
    __syncthreads();
    for (int i = t; i < ecnt; i += 256) {
        int p = eb[i];
        eb_s[i] = p;
        atomicAdd(&cnt_s[p >> 17], 1);
    }
    __syncthreads();
    int myc = cnt_s[t];
    off_s[t] = myc;
    __syncthreads();
    for (int off = 1; off < 256; off <<= 1) {
        int v = (t >= off) ? off_s[t - off] : 0;
        __syncthreads();
        off_s[t] += v;
        __syncthreads();
    }
    int excl = off_s[t] - myc;
    int node = (b << SH) + t;
    if (node < N) {
        row_ptr[node] = base + excl;
        dinv[node] = rsqrtf((float)myc + 1.0f);   // +1 = self loop
        if (node == N - 1) row_ptr[N] = base + excl + myc;   // sentinel == E
    }
    __syncthreads();
    off_s[t] = base + excl;
    __syncthreads();
    for (int i = t; i < ecnt; i += 256) {
        int p = eb_s[i];
        int slot = atomicAdd(&off_s[p >> 17], 1);
        csr_src[slot] = p & 0x1FFFF;
    }
}

// ---------- projection: y0' = dinv * (x @ W^T), stored bf16 ----------
__global__ __launch_bounds__(256) void gemm_kernel(const float* __restrict__ x,
                                                   const float* __restrict__ WT,
                                                   const float* __restrict__ dinv,
                                                   ushort_t* __restrict__ yb, int N) {
    __shared__ float Ws[DIN * DOUT];              // 32 KB
    __shared__ float xs[XROWS * XS_STRIDE];       // 16.9 KB
    int tid  = threadIdx.x;
    int row0 = blockIdx.x * XROWS;

    {
        const float4* s4 = (const float4*)WT;
        float4* d4 = (float4*)Ws;
        for (int j = tid; j < DIN * DOUT / 4; j += 256) d4[j] = s4[j];
    }
    for (int j = tid; j < XROWS * DIN / 4; j += 256) {
        int r  = j >> 5;
        int c4 = (j & 31) * 4;
        int grow = row0 + r;
        float4 v = {0.f, 0.f, 0.f, 0.f};
        if (grow < N) v = *(const float4*)&x[(size_t)grow * DIN + c4];
        *(float4*)&xs[r * XS_STRIDE + c4] = v;
    }
    __syncthreads();

    int g  = tid & 15;
    int rg = tid >> 4;
    int r0 = rg * 2;

    float4 acc0 = {}, acc1 = {};
    for (int kk = 0; kk < DIN; kk += 4) {
        float4 wv0 = *(const float4*)&Ws[(kk + 0) * DOUT + g * 4];
        float4 wv1 = *(const float4*)&Ws[(kk + 1) * DOUT + g * 4];
        float4 wv2 = *(const float4*)&Ws[(kk + 2) * DOUT + g * 4];
        float4 wv3 = *(const float4*)&Ws[(kk + 3) * DOUT + g * 4];
        float4 xv0 = *(const float4*)&xs[(r0 + 0) * XS_STRIDE + kk];
        float4 xv1 = *(const float4*)&xs[(r0 + 1) * XS_STRIDE + kk];
        acc0.x += xv0.x * wv0.x + xv0.y * wv1.x + xv0.z * wv2.x + xv0.w * wv3.x;
        acc0.y += xv0.x * wv0.y + xv0.y * wv1.y + xv0.z * wv2.y + xv0.w * wv3.y;
        acc0.z += xv0.x * wv0.z + xv0.y * wv1.z + xv0.z * wv2.z + xv0.w * wv3.z;
        acc0.w += xv0.x * wv0.w + xv0.y * wv1.w + xv0.z * wv2.w + xv0.w * wv3.w;
        acc1.x += xv1.x * wv0.x + xv1.y * wv1.x + xv1.z * wv2.x + xv1.w * wv3.x;
        acc1.y += xv1.x * wv0.y + xv1.y * wv1.y + xv1.z * wv2.y + xv1.w * wv3.y;
        acc1.z += xv1.x * wv0.z + xv1.y * wv1.z + xv1.z * wv2.z + xv1.w * wv3.z;
        acc1.w += xv1.x * wv0.w + xv1.y * wv1.w + xv1.z * wv2.w + xv1.w * wv3.w;
    }
    #pragma unroll
    for (int r = 0; r < 2; ++r) {
        int grow = row0 + r0 + r;
        if (grow < N) {
            float dv = dinv[grow];
            float4 a = r ? acc1 : acc0;
            ushort4 o;
            o.x = f2bf(a.x * dv); o.y = f2bf(a.y * dv);
            o.z = f2bf(a.z * dv); o.w = f2bf(a.w * dv);
            *(ushort4*)&yb[(size_t)grow * DOUT + g * 4] = o;
        }
    }
}

// unpack 4 dwords (8 bf16) and add into v2f acc pairs (v_pk_add_f32)
__device__ __forceinline__ void add_unpack2(v2f* acc, uint4 v) {
    unsigned u[4] = {v.x, v.y, v.z, v.w};
    #pragma unroll
    for (int d = 0; d < 4; ++d) {
        union { unsigned u; float f; } lo, hi;
        lo.u = u[d] << 16;
        hi.u = u[d] & 0xFFFF0000u;
        v2f p; p.x = lo.f; p.y = hi.f;
        acc[d] += p;
    }
}

// ---------- wide pull-gather: 2 rows per wave, interleaved load chains ----------
// wave = 8 slots x 8 fb per row; rows A,B alternate batches -> 4 VMEM in flight.
template <int FINAL>
__global__ __launch_bounds__(256) void gather_kernel(const int* __restrict__ row_ptr,
                                                     const int* __restrict__ csr_src,
                                                     const float* __restrict__ dinv,
                                                     const ushort_t* __restrict__ yin,
                                                     const float* __restrict__ bias,
                                                     ushort_t* __restrict__ yout,
                                                     float* __restrict__ out,
                                                     float* __restrict__ emb, int N) {
    int gw = blockIdx.x * 4 + (threadIdx.x >> 6);
    int rowA = gw * 2;
    if (rowA >= N) return;
    bool hasB = (rowA + 1) < N;
    int rowB = hasB ? rowA + 1 : rowA;

    int lane = threadIdx.x & 63;
    int fb   = lane & 7;
    int slot = lane >> 3;
    // row_ptr[rowA..rowA+2]: contiguous; rowB+1 <= N safe
    int startA = __builtin_amdgcn_readfirstlane(row_ptr[rowA]);
    int endA   = __builtin_amdgcn_readfirstlane(row_ptr[rowA + 1]);
    int endB   = __builtin_amdgcn_readfirstlane(row_ptr[rowB + 1]);
    int startB = hasB ? endA : startA;

    const char* ybase = (const char*)yin;
    unsigned fb16 = (unsigned)fb * 16u;

    v2f accA[4] = {}, accB[4] = {};

    int bA = startA, bB = startB;
    int degA = endA - startA, degB = endB - startB;
    int nfA = degA >> 3, nfB = degB >> 3;
    int nmin = min(nfA, nfB);
    for (int i = 0; i < nmin; ++i, bA += 8, bB += 8) {   // paired: 4 VMEM chains
        int sA = csr_src[bA + slot];
        int sB = csr_src[bB + slot];
        uint4 vA = *(const uint4*)(ybase + (((unsigned)sA << 7) + fb16));
        uint4 vB = *(const uint4*)(ybase + (((unsigned)sB << 7) + fb16));
        add_unpack2(accA, vA);
        add_unpack2(accB, vB);
    }
    for (int i = nmin; i < nfA; ++i, bA += 8) {          // leftover A
        int s = csr_src[bA + slot];
        uint4 v = *(const uint4*)(ybase + (((unsigned)s << 7) + fb16));
        add_unpack2(accA, v);
    }
    for (int i = nmin; i < nfB; ++i, bB += 8) {          // leftover B
        int s = csr_src[bB + slot];
        uint4 v = *(const uint4*)(ybase + (((unsigned)s << 7) + fb16));
        add_unpack2(accB, v);
    }
    {   // tails: rem edges in slots [0,rem), self loop in slot rem
        int remA = degA & 7;
        int sA = (slot < remA) ? csr_src[bA + slot] : rowA;
        uint4 vA = *(const uint4*)(ybase + (((unsigned)sA << 7) + fb16));
        if (slot <= remA) add_unpack2(accA, vA);
        int remB = degB & 7;
        int sB = (slot < remB) ? csr_src[bB + slot] : rowB;
        uint4 vB = *(const uint4*)(ybase + (((unsigned)sB << 7) + fb16));
        if (slot <= remB) add_unpack2(accB, vB);
    }

    #pragma unroll
    for (int pass = 0; pass < 2; ++pass) {
        if (pass == 1 && !hasB) break;
        v2f* a2 = pass ? accB : accA;
        int row = pass ? rowB : rowA;
        float acc[8] = {a2[0].x, a2[0].y, a2[1].x, a2[1].y,
                        a2[2].x, a2[2].y, a2[3].x, a2[3].y};
        #pragma unroll
        for (int m = 8; m <= 32; m <<= 1) {
            #pragma unroll
            for (int i = 0; i < 8; ++i) acc[i] += __shfl_xor(acc[i], m, 64);
        }
        float dv = dinv[row];
        if (!FINAL) {
            if (slot == 0) {
                float s2 = dv * dv;
                union { ushort_t us[8]; uint4 u; } o;
                #pragma unroll
                for (int i = 0; i < 8; ++i) o.us[i] = f2bf(acc[i] * s2);
                *(uint4*)(yout + (size_t)row * DOUT + fb * 8) = o.u;
            }
        } else {
            const float4* bp = (const float4*)(bias + fb * 8);
            float4 b0 = bp[0], b1 = bp[1];
            float e[8];
            e[0] = dv * acc[0] + b0.x; e[1] = dv * acc[1] + b0.y;
            e[2] = dv * acc[2] + b0.z; e[3] = dv * acc[3] + b0.w;
            e[4] = dv * acc[4] + b1.x; e[5] = dv * acc[5] + b1.y;
            e[6] = dv * acc[6] + b1.z; e[7] = dv * acc[7] + b1.w;
            float m = e[0];
            #pragma unroll
            for (int i = 1; i < 8; ++i) m = fmaxf(m, e[i]);
            #pragma unroll
            for (int o2 = 1; o2 <= 4; o2 <<= 1) m = fmaxf(m, __shfl_xor(m, o2, 64));
            float ss = 0.f;
            #pragma unroll
            for (int i = 0; i < 8; ++i) ss += __expf(e[i] - m);
            #pragma unroll
            for (int o2 = 1; o2 <= 4; o2 <<= 1) ss += __shfl_xor(ss, o2, 64);
            float lg = m + __logf(ss);
            if (slot == 0) {
                float4* ep = (float4*)(emb + (size_t)row * DOUT + fb * 8);
                ep[0] = make_float4(e[0], e[1], e[2], e[3]);
                ep[1] = make_float4(e[4], e[5], e[6], e[7]);
                float4* op = (float4*)(out + (size_t)row * DOUT + fb * 8);
                op[0] = make_float4(e[0] - lg, e[1] - lg, e[2] - lg, e[3] - lg);
                op[1] = make_float4(e[4] - lg, e[5] - lg, e[6] - lg, e[7] - lg);
            }
        }
    }
}

extern "C" void kernel_launch(void* const* d_in, const int* in_sizes, int n_in,
                              void* d_out, int out_size, void* d_ws, size_t ws_size,
                              hipStream_t stream) {
    const float* x    = (const float*)d_in[0];
    const int*   edge = (const int*)d_in[1];
    const float* W    = (const float*)d_in[2];
    const float* b    = (const float*)d_in[3];

    const int N = in_sizes[0] / DIN;   // 100000
    const int E = in_sizes[1] / 2;     // 1600000
    const int* src = edge;
    const int* dst = edge + E;

    float* out_ptr = (float*)d_out;                // [N,64] log_softmax
    float* emb_ptr = out_ptr + (size_t)N * DOUT;   // [N,64] emb

    const int B = (N + (1 << SH) - 1) >> SH;       // 391 buckets

    int*     cursor      = (int*)d_ws;
    float*   WT          = (float*)(cursor + BMAX);
    int*     row_ptr     = (int*)(WT + DIN * DOUT);
    float*   dinv        = (float*)(row_ptr + N + 1);
    int*     csr_src     = (int*)(dinv + N);
    int*     arena       = csr_src + E + 64;
    int*     binned      = arena;
    ushort_t* y0b        = (ushort_t*)arena;
    ushort_t* y1b        = y0b + (size_t)N * DOUT;

    // 1. CSR by dst + dinv; W -> WT transpose (cursor zeroed in init_kernel)
    init_kernel<<<8, 256, 0, stream>>>(cursor, csr_src + E, W, WT);
    bin_kernel<<<(E + BCHUNK - 1) / BCHUNK, 256, 0, stream>>>(src, dst, cursor, binned, E, B);
    csr_kernel<<<B, 256, 0, stream>>>(binned, cursor, row_ptr, dinv, csr_src, N);

    // 2. project + pre-scale: y0' = dinv * (x @ W^T)   (bf16)
    gemm_kernel<<<(N + XROWS - 1) / XROWS, 256, 0, stream>>>(x, WT, dinv, y0b, N);

    // 3. hop 1: y1' = dinv^2 * (y0'[row] + sum y0'[src])    (2 rows/wave)
    gather_kernel<0><<<(N + 7) / 8, 256, 0, stream>>>(row_ptr, csr_src, dinv, y0b, b,
                                                      y1b, nullptr, nullptr, N);

    // 4. hop 2 + bias + log_softmax, fused
    gather_kernel<1><<<(N + 7) / 8, 256, 0, stream>>>(row_ptr, csr_src, dinv, y1b, b,
                                                      nullptr, out_ptr, emb_ptr, N);
}

// Round 15
// 191.981 us; speedup vs baseline: 1.3213x; 1.0009x over previous
//
#include <hip/hip_runtime.h>

#define DIN 128
#define DOUT 64
#define SH 8            // nodes per bucket = 256
#define CAP 8192        // slots per bucket (avg ~4096, +64 sigma headroom)
#define BMAX 512
#define XS_STRIDE (DIN + 4)
#define XROWS 32        // x tile rows (LDS 49.6KB total -> 3 blocks/CU)
#define TPB 2           // x tiles per gemm block (W staged once)
#define BCHUNK 4096     // edges per bin block

typedef unsigned short ushort_t;
typedef float v2f __attribute__((ext_vector_type(2)));

__device__ __forceinline__ ushort_t f2bf(float f) {
    union { float f; unsigned u; } v; v.f = f;
    unsigned r = v.u + 0x7FFF + ((v.u >> 16) & 1);   // round-nearest-even
    return (ushort_t)(r >> 16);
}

// ---------- pass A: bin edges by dst>>SH, packed (ldst<<17)|src ----------
__global__ __launch_bounds__(256) void bin_kernel(const int* __restrict__ src,
                                                  const int* __restrict__ dst,
                                                  int* __restrict__ cursor,
                                                  int* __restrict__ binned, int E, int B) {
    __shared__ int hist_s[BMAX], gbase_s[BMAX], cur_s[BMAX];
    __shared__ int dst_s[BCHUNK];                 // 16 KB
    for (int i = threadIdx.x; i < B; i += 256) { hist_s[i] = 0; cur_s[i] = 0; }
    __syncthreads();
    int e0 = blockIdx.x * BCHUNK;
    int e1 = min(e0 + BCHUNK, E);
    int n  = e1 - e0;
    for (int i = threadIdx.x; i < n; i += 256) {
        int d = dst[e0 + i];
        dst_s[i] = d;
        atomicAdd(&hist_s[d >> SH], 1);
    }
    __syncthreads();
    for (int b = threadIdx.x; b < B; b += 256) {
        int h = hist_s[b];
        gbase_s[b] = h ? atomicAdd(&cursor[b], h) : 0;   // relative base (cursor starts 0)
    }
    __syncthreads();
    for (int i = threadIdx.x; i < n; i += 256) {
        int d = dst_s[i], s = src[e0 + i];
        int b = d >> SH;
        int off = atomicAdd(&cur_s[b], 1);
        int rel = gbase_s[b] + off;
        if (rel < CAP)
            binned[b * CAP + rel] = ((d & ((1 << SH) - 1)) << 17) | s;
    }
}

// zero cursor + csr pad, transpose W -> WT [128][64]
__global__ void init_kernel(int* cursor, int* csr_pad, const float* __restrict__ W,
                            float* __restrict__ WT) {
    int b = blockIdx.x * 256 + threadIdx.x;
    if (b < BMAX) cursor[b] = 0;
    if (b < 64) csr_pad[b] = 0;
    for (int j = b; j < DIN * DOUT; j += 2048)
        WT[j] = W[(j & 63) * DIN + (j >> 6)];
}

// ---------- pass B: per-bucket CSR build (bucket staged in LDS) ----------
__global__ __launch_bounds__(256) void csr_kernel(const int* __restrict__ binned,
                                                  const int* __restrict__ cursor,
                                                  int* __restrict__ row_ptr,
                                                  float* __restrict__ dinv,
                                                  int* __restrict__ csr_src, int N) {
    __shared__ int cnt_s[256], off_s[256], bsc[BMAX];
    __shared__ int eb_s[CAP];                     // 32 KB bucket stage
    int b = blockIdx.x;
    int t = threadIdx.x;

    int c0 = min(cursor[t], CAP);
    int c1 = min(cursor[t + 256], CAP);
    bsc[t] = c0; bsc[t + 256] = c1;
    __syncthreads();
    for (int off = 1; off < BMAX; off <<= 1) {
        int v0 = (t >= off) ? bsc[t - off] : 0;
        int v1 = (t + 256 >= off) ? bsc[t + 256 - off] : 0;
        __syncthreads();
        bsc[t] += v0; bsc[t + 256] += v1;
        __syncthreads();
    }
    int cb = min(cursor[b], CAP);                 // this bucket's count
    int base = bsc[b] - cb;                       // exclusive prefix
    int ecnt = cb;
    const int* eb = binned + (size_t)b * CAP;

    cnt_s[t] = 0;
    __syncthreads();
    for (int i = t; i < ecnt; i += 256) {
        int p = eb[i];
        eb_s[i] = p;
        atomicAdd(&cnt_s[p >> 17], 1);
    }
    __syncthreads();
    int myc = cnt_s[t];
    off_s[t] = myc;
    __syncthreads();
    for (int off = 1; off < 256; off <<= 1) {
        int v = (t >= off) ? off_s[t - off] : 0;
        __syncthreads();
        off_s[t] += v;
        __syncthreads();
    }
    int excl = off_s[t] - myc;
    int node = (b << SH) + t;
    if (node < N) {
        row_ptr[node] = base + excl;
        dinv[node] = rsqrtf((float)myc + 1.0f);   // +1 = self loop
        if (node == N - 1) row_ptr[N] = base + excl + myc;   // sentinel == E
    }
    __syncthreads();
    off_s[t] = base + excl;
    __syncthreads();
    for (int i = t; i < ecnt; i += 256) {
        int p = eb_s[i];
        int slot = atomicAdd(&off_s[p >> 17], 1);
        csr_src[slot] = p & 0x1FFFF;
    }
}

// ---------- projection: y0' = dinv * (x @ W^T), stored bf16 ----------
// TPB tiles per block: W staged ONCE, reused across tiles.
__global__ __launch_bounds__(256) void gemm_kernel(const float* __restrict__ x,
                                                   const float* __restrict__ WT,
                                                   const float* __restrict__ dinv,
                                                   ushort_t* __restrict__ yb, int N) {
    __shared__ float Ws[DIN * DOUT];              // 32 KB
    __shared__ float xs[XROWS * XS_STRIDE];       // 16.9 KB
    int tid = threadIdx.x;

    {
        const float4* s4 = (const float4*)WT;
        float4* d4 = (float4*)Ws;
        for (int j = tid; j < DIN * DOUT / 4; j += 256) d4[j] = s4[j];
    }

    int g  = tid & 15;
    int rg = tid >> 4;
    int r0 = rg * 2;

    for (int tile = 0; tile < TPB; ++tile) {
        int row0 = (blockIdx.x * TPB + tile) * XROWS;
        if (row0 >= N) break;
        if (tile) __syncthreads();                // xs reuse guard
        for (int j = tid; j < XROWS * DIN / 4; j += 256) {
            int r  = j >> 5;
            int c4 = (j & 31) * 4;
            int grow = row0 + r;
            float4 v = {0.f, 0.f, 0.f, 0.f};
            if (grow < N) v = *(const float4*)&x[(size_t)grow * DIN + c4];
            *(float4*)&xs[r * XS_STRIDE + c4] = v;
        }
        __syncthreads();

        float4 acc0 = {}, acc1 = {};
        for (int kk = 0; kk < DIN; kk += 4) {
            float4 wv0 = *(const float4*)&Ws[(kk + 0) * DOUT + g * 4];
            float4 wv1 = *(const float4*)&Ws[(kk + 1) * DOUT + g * 4];
            float4 wv2 = *(const float4*)&Ws[(kk + 2) * DOUT + g * 4];
            float4 wv3 = *(const float4*)&Ws[(kk + 3) * DOUT + g * 4];
            float4 xv0 = *(const float4*)&xs[(r0 + 0) * XS_STRIDE + kk];
            float4 xv1 = *(const float4*)&xs[(r0 + 1) * XS_STRIDE + kk];
            acc0.x += xv0.x * wv0.x + xv0.y * wv1.x + xv0.z * wv2.x + xv0.w * wv3.x;
            acc0.y += xv0.x * wv0.y + xv0.y * wv1.y + xv0.z * wv2.y + xv0.w * wv3.y;
            acc0.z += xv0.x * wv0.z + xv0.y * wv1.z + xv0.z * wv2.z + xv0.w * wv3.z;
            acc0.w += xv0.x * wv0.w + xv0.y * wv1.w + xv0.z * wv2.w + xv0.w * wv3.w;
            acc1.x += xv1.x * wv0.x + xv1.y * wv1.x + xv1.z * wv2.x + xv1.w * wv3.x;
            acc1.y += xv1.x * wv0.y + xv1.y * wv1.y + xv1.z * wv2.y + xv1.w * wv3.y;
            acc1.z += xv1.x * wv0.z + xv1.y * wv1.z + xv1.z * wv2.z + xv1.w * wv3.z;
            acc1.w += xv1.x * wv0.w + xv1.y * wv1.w + xv1.z * wv2.w + xv1.w * wv3.w;
        }
        #pragma unroll
        for (int r = 0; r < 2; ++r) {
            int grow = row0 + r0 + r;
            if (grow < N) {
                float dv = dinv[grow];
                float4 a = r ? acc1 : acc0;
                ushort4 o;
                o.x = f2bf(a.x * dv); o.y = f2bf(a.y * dv);
                o.z = f2bf(a.z * dv); o.w = f2bf(a.w * dv);
                *(ushort4*)&yb[(size_t)grow * DOUT + g * 4] = o;
            }
        }
    }
}

// unpack 4 dwords (8 bf16) and add into v2f acc pairs (v_pk_add_f32)
__device__ __forceinline__ void add_unpack2(v2f* acc, uint4 v) {
    unsigned u[4] = {v.x, v.y, v.z, v.w};
    #pragma unroll
    for (int d = 0; d < 4; ++d) {
        union { unsigned u; float f; } lo, hi;
        lo.u = u[d] << 16;
        hi.u = u[d] & 0xFFFF0000u;
        v2f p; p.x = lo.f; p.y = hi.f;
        acc[d] += p;
    }
}

// ---------- wide pull-gather (r13 proven): wave = 8 slots x 8 fb; self in tail ----------
template <int FINAL>
__global__ __launch_bounds__(256) void gather_kernel(const int* __restrict__ row_ptr,
                                                     const int* __restrict__ csr_src,
                                                     const float* __restrict__ dinv,
                                                     const ushort_t* __restrict__ yin,
                                                     const float* __restrict__ bias,
                                                     ushort_t* __restrict__ yout,
                                                     float* __restrict__ out,
                                                     float* __restrict__ emb, int N) {
    int row = blockIdx.x * 4 + (threadIdx.x >> 6);
    if (row >= N) return;
    int lane = threadIdx.x & 63;
    int fb   = lane & 7;    // feature block: features [fb*8, fb*8+8)
    int slot = lane >> 3;   // edge slot within a batch of 8
    int start = __builtin_amdgcn_readfirstlane(row_ptr[row]);
    int end   = __builtin_amdgcn_readfirstlane(row_ptr[row + 1]);

    const char* ybase = (const char*)yin;
    unsigned fb16 = (unsigned)fb * 16u;

    v2f acc2[4] = {};

    int b = start;
    int deg = end - start;
    int nfull = deg >> 3;
    #pragma unroll 2
    for (int i = 0; i < nfull; ++i, b += 8) {        // unmasked full batches
        int s = csr_src[b + slot];                   // 32B span per batch
        uint4 v = *(const uint4*)(ybase + (((unsigned)s << 7) + fb16));
        add_unpack2(acc2, v);
    }
    // tail batch: rem edges in slots [0,rem), SELF LOOP in slot rem
    {
        int rem = deg & 7;
        int s = (slot < rem) ? csr_src[b + slot] : row;   // pad-safe (csr pad >= 8)
        uint4 v = *(const uint4*)(ybase + (((unsigned)s << 7) + fb16));
        if (slot <= rem) add_unpack2(acc2, v);
    }

    float acc[8] = {acc2[0].x, acc2[0].y, acc2[1].x, acc2[1].y,
                    acc2[2].x, acc2[2].y, acc2[3].x, acc2[3].y};

    // sum the 8 slots: xor over slot bits
    #pragma unroll
    for (int m = 8; m <= 32; m <<= 1) {
        #pragma unroll
        for (int i = 0; i < 8; ++i) acc[i] += __shfl_xor(acc[i], m, 64);
    }

    float dv = dinv[row];
    if (!FINAL) {
        if (slot == 0) {
            float s2 = dv * dv;
            union { ushort_t us[8]; uint4 u; } o;
            #pragma unroll
            for (int i = 0; i < 8; ++i) o.us[i] = f2bf(acc[i] * s2);
            *(uint4*)(yout + (size_t)row * DOUT + fb * 8) = o.u;
        }
    } else {
        const float4* bp = (const float4*)(bias + fb * 8);
        float4 b0 = bp[0], b1 = bp[1];
        float e[8];
        e[0] = dv * acc[0] + b0.x; e[1] = dv * acc[1] + b0.y;
        e[2] = dv * acc[2] + b0.z; e[3] = dv * acc[3] + b0.w;
        e[4] = dv * acc[4] + b1.x; e[5] = dv * acc[5] + b1.y;
        e[6] = dv * acc[6] + b1.z; e[7] = dv * acc[7] + b1.w;
        float m = e[0];
        #pragma unroll
        for (int i = 1; i < 8; ++i) m = fmaxf(m, e[i]);
        #pragma unroll
        for (int o2 = 1; o2 <= 4; o2 <<= 1) m = fmaxf(m, __shfl_xor(m, o2, 64));
        float ss = 0.f;
        #pragma unroll
        for (int i = 0; i < 8; ++i) ss += __expf(e[i] - m);   // fast exp
        #pragma unroll
        for (int o2 = 1; o2 <= 4; o2 <<= 1) ss += __shfl_xor(ss, o2, 64);
        float lg = m + __logf(ss);                             // fast log
        if (slot == 0) {
            float4* ep = (float4*)(emb + (size_t)row * DOUT + fb * 8);
            ep[0] = make_float4(e[0], e[1], e[2], e[3]);
            ep[1] = make_float4(e[4], e[5], e[6], e[7]);
            float4* op = (float4*)(out + (size_t)row * DOUT + fb * 8);
            op[0] = make_float4(e[0] - lg, e[1] - lg, e[2] - lg, e[3] - lg);
            op[1] = make_float4(e[4] - lg, e[5] - lg, e[6] - lg, e[7] - lg);
        }
    }
}

extern "C" void kernel_launch(void* const* d_in, const int* in_sizes, int n_in,
                              void* d_out, int out_size, void* d_ws, size_t ws_size,
                              hipStream_t stream) {
    const float* x    = (const float*)d_in[0];
    const int*   edge = (const int*)d_in[1];
    const float* W    = (const float*)d_in[2];
    const float* b    = (const float*)d_in[3];

    const int N = in_sizes[0] / DIN;   // 100000
    const int E = in_sizes[1] / 2;     // 1600000
    const int* src = edge;
    const int* dst = edge + E;

    float* out_ptr = (float*)d_out;                // [N,64] log_softmax
    float* emb_ptr = out_ptr + (size_t)N * DOUT;   // [N,64] emb

    const int B = (N + (1 << SH) - 1) >> SH;       // 391 buckets

    int*     cursor      = (int*)d_ws;
    float*   WT          = (float*)(cursor + BMAX);
    int*     row_ptr     = (int*)(WT + DIN * DOUT);
    float*   dinv        = (float*)(row_ptr + N + 1);
    int*     csr_src     = (int*)(dinv + N);
    int*     arena       = csr_src + E + 64;
    int*     binned      = arena;
    ushort_t* y0b        = (ushort_t*)arena;
    ushort_t* y1b        = y0b + (size_t)N * DOUT;

    // 1. CSR by dst + dinv; W -> WT transpose (cursor zeroed in init_kernel)
    init_kernel<<<8, 256, 0, stream>>>(cursor, csr_src + E, W, WT);
    bin_kernel<<<(E + BCHUNK - 1) / BCHUNK, 256, 0, stream>>>(src, dst, cursor, binned, E, B);
    csr_kernel<<<B, 256, 0, stream>>>(binned, cursor, row_ptr, dinv, csr_src, N);

    // 2. project + pre-scale: y0' = dinv * (x @ W^T)   (bf16), 2 tiles/block
    gemm_kernel<<<(N + TPB * XROWS - 1) / (TPB * XROWS), 256, 0, stream>>>(x, WT, dinv, y0b, N);

    // 3. hop 1: y1' = dinv^2 * (y0'[row] + sum y0'[src])
    gather_kernel<0><<<(N + 3) / 4, 256, 0, stream>>>(row_ptr, csr_src, dinv, y0b, b,
                                                      y1b, nullptr, nullptr, N);

    // 4. hop 2 + bias + log_softmax, fused
    gather_kernel<1><<<(N + 3) / 4, 256, 0, stream>>>(row_ptr, csr_src, dinv, y1b, b,
                                                      nullptr, out_ptr, emb_ptr, N);
}